// Round 1
// baseline (7684.724 us; speedup 1.0000x reference)
//
#include <hip/hip_runtime.h>

#define F_IN 512
#define HID 128
#define KHOPS 10
#define COUT 10

// ---------------- GEMM: h = x @ W + b ; hidden = fw0 * h ----------------
#define BM 64
#define BK 16

__global__ __launch_bounds__(256) void gemm_in_kernel(
    const float* __restrict__ x, const float* __restrict__ W,
    const float* __restrict__ bias, const float* __restrict__ fwp,
    float* __restrict__ h, float* __restrict__ hidden, int n)
{
    __shared__ float xs[BM][BK + 1];
    __shared__ float wsb[BK][HID];
    const int t = threadIdx.x;
    const int row0 = blockIdx.x * BM;
    const int ty = t >> 4, tx = t & 15;

    float acc[4][8];
#pragma unroll
    for (int i = 0; i < 4; ++i)
#pragma unroll
        for (int j = 0; j < 8; ++j) acc[i][j] = 0.f;

    const int xr = t >> 2;        // 0..63
    const int xk = (t & 3) * 4;   // 0,4,8,12

    for (int k0 = 0; k0 < F_IN; k0 += BK) {
        float4 xv = make_float4(0.f, 0.f, 0.f, 0.f);
        if (row0 + xr < n)
            xv = *(const float4*)(x + (size_t)(row0 + xr) * F_IN + k0 + xk);
        xs[xr][xk] = xv.x; xs[xr][xk + 1] = xv.y;
        xs[xr][xk + 2] = xv.z; xs[xr][xk + 3] = xv.w;
#pragma unroll
        for (int rep = 0; rep < 2; ++rep) {
            int idx = t + rep * 256;
            int kr = idx >> 5;          // 0..15
            int c4 = (idx & 31) * 4;    // 0..124
            *(float4*)(&wsb[kr][c4]) = *(const float4*)(W + (size_t)(k0 + kr) * HID + c4);
        }
        __syncthreads();
#pragma unroll
        for (int kk = 0; kk < BK; ++kk) {
            float a0 = xs[ty * 4 + 0][kk];
            float a1 = xs[ty * 4 + 1][kk];
            float a2 = xs[ty * 4 + 2][kk];
            float a3 = xs[ty * 4 + 3][kk];
            const float4 b0 = *(const float4*)(&wsb[kk][tx * 8]);
            const float4 b1 = *(const float4*)(&wsb[kk][tx * 8 + 4]);
            acc[0][0] = fmaf(a0, b0.x, acc[0][0]); acc[0][1] = fmaf(a0, b0.y, acc[0][1]);
            acc[0][2] = fmaf(a0, b0.z, acc[0][2]); acc[0][3] = fmaf(a0, b0.w, acc[0][3]);
            acc[0][4] = fmaf(a0, b1.x, acc[0][4]); acc[0][5] = fmaf(a0, b1.y, acc[0][5]);
            acc[0][6] = fmaf(a0, b1.z, acc[0][6]); acc[0][7] = fmaf(a0, b1.w, acc[0][7]);
            acc[1][0] = fmaf(a1, b0.x, acc[1][0]); acc[1][1] = fmaf(a1, b0.y, acc[1][1]);
            acc[1][2] = fmaf(a1, b0.z, acc[1][2]); acc[1][3] = fmaf(a1, b0.w, acc[1][3]);
            acc[1][4] = fmaf(a1, b1.x, acc[1][4]); acc[1][5] = fmaf(a1, b1.y, acc[1][5]);
            acc[1][6] = fmaf(a1, b1.z, acc[1][6]); acc[1][7] = fmaf(a1, b1.w, acc[1][7]);
            acc[2][0] = fmaf(a2, b0.x, acc[2][0]); acc[2][1] = fmaf(a2, b0.y, acc[2][1]);
            acc[2][2] = fmaf(a2, b0.z, acc[2][2]); acc[2][3] = fmaf(a2, b0.w, acc[2][3]);
            acc[2][4] = fmaf(a2, b1.x, acc[2][4]); acc[2][5] = fmaf(a2, b1.y, acc[2][5]);
            acc[2][6] = fmaf(a2, b1.z, acc[2][6]); acc[2][7] = fmaf(a2, b1.w, acc[2][7]);
            acc[3][0] = fmaf(a3, b0.x, acc[3][0]); acc[3][1] = fmaf(a3, b0.y, acc[3][1]);
            acc[3][2] = fmaf(a3, b0.z, acc[3][2]); acc[3][3] = fmaf(a3, b0.w, acc[3][3]);
            acc[3][4] = fmaf(a3, b1.x, acc[3][4]); acc[3][5] = fmaf(a3, b1.y, acc[3][5]);
            acc[3][6] = fmaf(a3, b1.z, acc[3][6]); acc[3][7] = fmaf(a3, b1.w, acc[3][7]);
        }
        __syncthreads();
    }

    const float fw0 = fwp[0];
    const float4 bv0 = *(const float4*)(bias + tx * 8);
    const float4 bv1 = *(const float4*)(bias + tx * 8 + 4);
#pragma unroll
    for (int i = 0; i < 4; ++i) {
        int row = row0 + ty * 4 + i;
        if (row >= n) continue;
        float4 o0, o1;
        o0.x = acc[i][0] + bv0.x; o0.y = acc[i][1] + bv0.y;
        o0.z = acc[i][2] + bv0.z; o0.w = acc[i][3] + bv0.w;
        o1.x = acc[i][4] + bv1.x; o1.y = acc[i][5] + bv1.y;
        o1.z = acc[i][6] + bv1.z; o1.w = acc[i][7] + bv1.w;
        float* hp = h + (size_t)row * HID + tx * 8;
        *(float4*)(hp) = o0;
        *(float4*)(hp + 4) = o1;
        float4 d0, d1;
        d0.x = fw0 * o0.x; d0.y = fw0 * o0.y; d0.z = fw0 * o0.z; d0.w = fw0 * o0.w;
        d1.x = fw0 * o1.x; d1.y = fw0 * o1.y; d1.z = fw0 * o1.z; d1.w = fw0 * o1.w;
        float* dp = hidden + (size_t)row * HID + tx * 8;
        *(float4*)(dp) = d0;
        *(float4*)(dp + 4) = d1;
    }
}

// ---------------- CSR build ----------------
__global__ void hist_kernel(const int* __restrict__ rows, int E, int* __restrict__ cnt)
{
    for (int i = blockIdx.x * blockDim.x + threadIdx.x; i < E; i += gridDim.x * blockDim.x)
        atomicAdd(&cnt[rows[i]], 1);
}

__global__ __launch_bounds__(1024) void scan_kernel(
    const int* __restrict__ cnt, int* __restrict__ rowptr, int* __restrict__ pos, int n)
{
    __shared__ int sd[1024];
    __shared__ int sbase;
    const int t = threadIdx.x;
    if (t == 0) { sbase = 0; rowptr[0] = 0; }
    __syncthreads();
    for (int start = 0; start < n; start += 1024) {
        int i = start + t;
        int v = (i < n) ? cnt[i] : 0;
        sd[t] = v;
        __syncthreads();
        for (int off = 1; off < 1024; off <<= 1) {
            int y = (t >= off) ? sd[t - off] : 0;
            __syncthreads();
            sd[t] += y;
            __syncthreads();
        }
        if (i < n) {
            int incl = sbase + sd[t];
            rowptr[i + 1] = incl;
            pos[i] = incl - v;   // exclusive = start position
        }
        __syncthreads();
        if (t == 0) sbase += sd[1023];
        __syncthreads();
    }
}

__global__ void scatter_kernel(const int* __restrict__ rows, const int* __restrict__ cols,
                               const float* __restrict__ w, int E,
                               int* __restrict__ pos, int2* __restrict__ cw)
{
    for (int i = blockIdx.x * blockDim.x + threadIdx.x; i < E; i += gridDim.x * blockDim.x) {
        int r = rows[i];
        int p = atomicAdd(&pos[r], 1);
        cw[p] = make_int2(cols[i], __float_as_int(w[i]));
    }
}

// ---------------- SpMM (pull, one wave per row) + hidden accumulation ----------------
__global__ __launch_bounds__(256) void spmm_kernel(
    const int* __restrict__ rowptr, const int2* __restrict__ cw,
    const float* __restrict__ hin, float* __restrict__ hout,
    float* __restrict__ hidden, const float* __restrict__ fwp, int n)
{
    const int wid = (blockIdx.x * blockDim.x + threadIdx.x) >> 6;
    if (wid >= n) return;
    const int lane = threadIdx.x & 63;
    const int s = rowptr[wid];
    const int e = rowptr[wid + 1];
    float2 acc = make_float2(0.f, 0.f);
    for (int i = s; i < e; ++i) {
        int2 p = cw[i];
        float w = __int_as_float(p.y);
        const float2 hv = *(const float2*)(hin + (size_t)p.x * HID + lane * 2);
        acc.x = fmaf(w, hv.x, acc.x);
        acc.y = fmaf(w, hv.y, acc.y);
    }
    const size_t o = (size_t)wid * HID + lane * 2;
    *(float2*)(hout + o) = acc;
    const float fw = fwp[0];
    float2 hd = *(const float2*)(hidden + o);
    hd.x = fmaf(fw, acc.x, hd.x);
    hd.y = fmaf(fw, acc.y, hd.y);
    *(float2*)(hidden + o) = hd;
}

// ---------------- z += hidden @ Wout_branch (+ b_out on init) ----------------
__global__ __launch_bounds__(256) void zacc_kernel(
    const float* __restrict__ hidden, const float* __restrict__ Wout,
    const float* __restrict__ bout, float* __restrict__ z, int initf, int n)
{
    const int wid = (blockIdx.x * blockDim.x + threadIdx.x) >> 6;
    if (wid >= n) return;
    const int lane = threadIdx.x & 63;
    const float2 hv = *(const float2*)(hidden + (size_t)wid * HID + lane * 2);
    const int f0 = lane * 2;
    float val = 0.f;
#pragma unroll
    for (int c = 0; c < COUT; ++c) {
        float pp = hv.x * Wout[f0 * COUT + c] + hv.y * Wout[(f0 + 1) * COUT + c];
#pragma unroll
        for (int off = 32; off > 0; off >>= 1) pp += __shfl_xor(pp, off);
        if (lane == c) val = pp;
    }
    if (lane < COUT) {
        size_t o = (size_t)wid * COUT + lane;
        if (initf) z[o] = val + bout[lane];
        else z[o] += val;
    }
}

// ---------------- log_softmax in place ----------------
__global__ void logsm_kernel(float* __restrict__ z, int n)
{
    const int r = blockIdx.x * blockDim.x + threadIdx.x;
    if (r >= n) return;
    float v[COUT];
    float m = -1e30f;
#pragma unroll
    for (int c = 0; c < COUT; ++c) { v[c] = z[(size_t)r * COUT + c]; m = fmaxf(m, v[c]); }
    float s = 0.f;
#pragma unroll
    for (int c = 0; c < COUT; ++c) s += expf(v[c] - m);
    const float l = logf(s) + m;
#pragma unroll
    for (int c = 0; c < COUT; ++c) z[(size_t)r * COUT + c] = v[c] - l;
}

extern "C" void kernel_launch(void* const* d_in, const int* in_sizes, int n_in,
                              void* d_out, int out_size, void* d_ws, size_t ws_size,
                              hipStream_t stream)
{
    const float* x    = (const float*)d_in[0];
    const int*   ei1  = (const int*)d_in[1];
    const float* ew1  = (const float*)d_in[2];
    const int*   ei2  = (const int*)d_in[3];
    const float* ew2  = (const float*)d_in[4];
    const float* Win  = (const float*)d_in[5];
    const float* bin  = (const float*)d_in[6];
    const float* fW   = (const float*)d_in[7];
    const float* Wout = (const float*)d_in[8];
    const float* bout = (const float*)d_in[9];
    const int n  = in_sizes[0] / F_IN;
    const int E1 = in_sizes[2];
    const int E2 = in_sizes[4];
    const int Emax = E1 > E2 ? E1 : E2;
    float* z = (float*)d_out;

    char* p = (char*)d_ws;
    auto alloc = [&](size_t bytes) { char* r = p; p += (bytes + 255) & ~(size_t)255; return r; };
    float* hA   = (float*)alloc((size_t)n * HID * 4);
    float* hB   = (float*)alloc((size_t)n * HID * 4);
    float* hid  = (float*)alloc((size_t)n * HID * 4);
    int*   cnt  = (int*)alloc((size_t)n * 4);
    int*   rowp = (int*)alloc((size_t)(n + 1) * 4);
    int*   pos  = (int*)alloc((size_t)n * 4);
    int2*  cw   = (int2*)alloc((size_t)Emax * 8);

    const int rowBlocks = (n + 3) / 4;   // 4 waves (rows) per 256-thread block

    for (int br = 0; br < 2; ++br) {
        const int*   ei = br ? ei2 : ei1;
        const float* ew = br ? ew2 : ew1;
        const int    E  = br ? E2 : E1;

        hipMemsetAsync(cnt, 0, (size_t)n * 4, stream);
        hipLaunchKernelGGL(hist_kernel, dim3(1024), dim3(256), 0, stream, ei, E, cnt);
        hipLaunchKernelGGL(scan_kernel, dim3(1), dim3(1024), 0, stream, cnt, rowp, pos, n);
        hipLaunchKernelGGL(scatter_kernel, dim3(1024), dim3(256), 0, stream,
                           ei, ei + E, ew, E, pos, cw);

        hipLaunchKernelGGL(gemm_in_kernel, dim3((n + BM - 1) / BM), dim3(256), 0, stream,
                           x, Win + (size_t)br * F_IN * HID, bin + (size_t)br * HID,
                           fW + (size_t)br * (KHOPS + 1), hA, hid, n);

        float* cur = hA; float* nxt = hB;
        for (int k = 0; k < KHOPS; ++k) {
            hipLaunchKernelGGL(spmm_kernel, dim3(rowBlocks), dim3(256), 0, stream,
                               rowp, cw, cur, nxt, hid,
                               fW + (size_t)br * (KHOPS + 1) + k + 1, n);
            float* tmp = cur; cur = nxt; nxt = tmp;
        }

        hipLaunchKernelGGL(zacc_kernel, dim3(rowBlocks), dim3(256), 0, stream,
                           hid, Wout + (size_t)br * HID * COUT, bout, z, br == 0 ? 1 : 0, n);
    }
    hipLaunchKernelGGL(logsm_kernel, dim3((n + 255) / 256), dim3(256), 0, stream, z, n);
}

// Round 2
// 5984.802 us; speedup vs baseline: 1.2840x; 1.2840x over previous
//
#include <hip/hip_runtime.h>

#define F_IN 512
#define HID 128
#define KHOPS 10
#define COUT 10

// ---------------- GEMM: h = x @ W + b ----------------
#define BM 64
#define BK 16

__global__ __launch_bounds__(256) void gemm_in_kernel(
    const float* __restrict__ x, const float* __restrict__ W,
    const float* __restrict__ bias, float* __restrict__ h, int n)
{
    __shared__ float xs[BM][BK + 1];
    __shared__ float wsb[BK][HID];
    const int t = threadIdx.x;
    const int row0 = blockIdx.x * BM;
    const int ty = t >> 4, tx = t & 15;

    float acc[4][8];
#pragma unroll
    for (int i = 0; i < 4; ++i)
#pragma unroll
        for (int j = 0; j < 8; ++j) acc[i][j] = 0.f;

    const int xr = t >> 2;        // 0..63
    const int xk = (t & 3) * 4;   // 0,4,8,12

    for (int k0 = 0; k0 < F_IN; k0 += BK) {
        float4 xv = make_float4(0.f, 0.f, 0.f, 0.f);
        if (row0 + xr < n)
            xv = *(const float4*)(x + (size_t)(row0 + xr) * F_IN + k0 + xk);
        xs[xr][xk] = xv.x; xs[xr][xk + 1] = xv.y;
        xs[xr][xk + 2] = xv.z; xs[xr][xk + 3] = xv.w;
#pragma unroll
        for (int rep = 0; rep < 2; ++rep) {
            int idx = t + rep * 256;
            int kr = idx >> 5;          // 0..15
            int c4 = (idx & 31) * 4;    // 0..124
            *(float4*)(&wsb[kr][c4]) = *(const float4*)(W + (size_t)(k0 + kr) * HID + c4);
        }
        __syncthreads();
#pragma unroll
        for (int kk = 0; kk < BK; ++kk) {
            float a0 = xs[ty * 4 + 0][kk];
            float a1 = xs[ty * 4 + 1][kk];
            float a2 = xs[ty * 4 + 2][kk];
            float a3 = xs[ty * 4 + 3][kk];
            const float4 b0 = *(const float4*)(&wsb[kk][tx * 8]);
            const float4 b1 = *(const float4*)(&wsb[kk][tx * 8 + 4]);
            acc[0][0] = fmaf(a0, b0.x, acc[0][0]); acc[0][1] = fmaf(a0, b0.y, acc[0][1]);
            acc[0][2] = fmaf(a0, b0.z, acc[0][2]); acc[0][3] = fmaf(a0, b0.w, acc[0][3]);
            acc[0][4] = fmaf(a0, b1.x, acc[0][4]); acc[0][5] = fmaf(a0, b1.y, acc[0][5]);
            acc[0][6] = fmaf(a0, b1.z, acc[0][6]); acc[0][7] = fmaf(a0, b1.w, acc[0][7]);
            acc[1][0] = fmaf(a1, b0.x, acc[1][0]); acc[1][1] = fmaf(a1, b0.y, acc[1][1]);
            acc[1][2] = fmaf(a1, b0.z, acc[1][2]); acc[1][3] = fmaf(a1, b0.w, acc[1][3]);
            acc[1][4] = fmaf(a1, b1.x, acc[1][4]); acc[1][5] = fmaf(a1, b1.y, acc[1][5]);
            acc[1][6] = fmaf(a1, b1.z, acc[1][6]); acc[1][7] = fmaf(a1, b1.w, acc[1][7]);
            acc[2][0] = fmaf(a2, b0.x, acc[2][0]); acc[2][1] = fmaf(a2, b0.y, acc[2][1]);
            acc[2][2] = fmaf(a2, b0.z, acc[2][2]); acc[2][3] = fmaf(a2, b0.w, acc[2][3]);
            acc[2][4] = fmaf(a2, b1.x, acc[2][4]); acc[2][5] = fmaf(a2, b1.y, acc[2][5]);
            acc[2][6] = fmaf(a2, b1.z, acc[2][6]); acc[2][7] = fmaf(a2, b1.w, acc[2][7]);
            acc[3][0] = fmaf(a3, b0.x, acc[3][0]); acc[3][1] = fmaf(a3, b0.y, acc[3][1]);
            acc[3][2] = fmaf(a3, b0.z, acc[3][2]); acc[3][3] = fmaf(a3, b0.w, acc[3][3]);
            acc[3][4] = fmaf(a3, b1.x, acc[3][4]); acc[3][5] = fmaf(a3, b1.y, acc[3][5]);
            acc[3][6] = fmaf(a3, b1.z, acc[3][6]); acc[3][7] = fmaf(a3, b1.w, acc[3][7]);
        }
        __syncthreads();
    }

    const float4 bv0 = *(const float4*)(bias + tx * 8);
    const float4 bv1 = *(const float4*)(bias + tx * 8 + 4);
#pragma unroll
    for (int i = 0; i < 4; ++i) {
        int row = row0 + ty * 4 + i;
        if (row >= n) continue;
        float4 o0, o1;
        o0.x = acc[i][0] + bv0.x; o0.y = acc[i][1] + bv0.y;
        o0.z = acc[i][2] + bv0.z; o0.w = acc[i][3] + bv0.w;
        o1.x = acc[i][4] + bv1.x; o1.y = acc[i][5] + bv1.y;
        o1.z = acc[i][6] + bv1.z; o1.w = acc[i][7] + bv1.w;
        float* hp = h + (size_t)row * HID + tx * 8;
        *(float4*)(hp) = o0;
        *(float4*)(hp + 4) = o1;
    }
}

// ---------------- CSR build ----------------
__global__ void hist_kernel(const int* __restrict__ rows, int E, int* __restrict__ cnt)
{
    for (int i = blockIdx.x * blockDim.x + threadIdx.x; i < E; i += gridDim.x * blockDim.x)
        atomicAdd(&cnt[rows[i]], 1);
}

// single block, 256 threads, chunked serial scan (3 phases, 2 barriers)
__global__ __launch_bounds__(256) void scan_kernel(
    const int* __restrict__ cnt, int* __restrict__ rowptr, int* __restrict__ pos, int n)
{
    __shared__ int ssum[256];
    const int t = threadIdx.x;
    const int chunk = (n + 255) / 256;
    const int start = t * chunk;
    const int end = (start + chunk < n) ? start + chunk : n;
    int sum = 0;
    for (int i = start; i < end; ++i) sum += cnt[i];
    ssum[t] = sum;
    __syncthreads();
    if (t == 0) {
        int run = 0;
        for (int i = 0; i < 256; ++i) { int v = ssum[i]; ssum[i] = run; run += v; }
        rowptr[0] = 0;
    }
    __syncthreads();
    int run = ssum[t];
    for (int i = start; i < end; ++i) {
        int v = cnt[i];
        pos[i] = run;
        run += v;
        rowptr[i + 1] = run;
    }
}

__global__ void scatter_kernel(const int* __restrict__ rows, const int* __restrict__ cols,
                               const float* __restrict__ w, int E,
                               int* __restrict__ pos, int2* __restrict__ cw)
{
    for (int i = blockIdx.x * blockDim.x + threadIdx.x; i < E; i += gridDim.x * blockDim.x) {
        int r = rows[i];
        int p = atomicAdd(&pos[r], 1);
        cw[p] = make_int2(cols[i], __float_as_int(w[i]));
    }
}

// ---------------- SpMM (pull, one wave per row) + fused z accumulation ----------------
// hout[row] = sum_e w_e * hin[col_e]     (skipped when storeH == 0)
// z[row]   += fw * (hout_row @ Wout)
__global__ __launch_bounds__(256) void spmm_kernel(
    const int* __restrict__ rowptr, const int2* __restrict__ cw,
    const float* __restrict__ hin, float* __restrict__ hout,
    const float* __restrict__ Wout, float* __restrict__ z,
    const float* __restrict__ fwp, int storeH, int n)
{
    const int wid = (blockIdx.x * blockDim.x + threadIdx.x) >> 6;
    if (wid >= n) return;
    const int lane = threadIdx.x & 63;

    // per-lane W_out rows for features 2*lane, 2*lane+1 (loaded once, overlap edge loop)
    float w0[COUT], w1[COUT];
    const float* wp = Wout + (size_t)(lane * 2) * COUT;
#pragma unroll
    for (int c = 0; c < COUT; ++c) { w0[c] = wp[c]; w1[c] = wp[COUT + c]; }

    const int s = rowptr[wid];
    const int e = rowptr[wid + 1];
    const float* hbase = hin + lane * 2;

    float2 acc = make_float2(0.f, 0.f);
    int i = s;
    const int e4 = s + ((e - s) & ~3);
    for (; i < e4; i += 4) {
        const int2 p0 = cw[i];
        const int2 p1 = cw[i + 1];
        const int2 p2 = cw[i + 2];
        const int2 p3 = cw[i + 3];
        const float2 g0 = *(const float2*)(hbase + (size_t)p0.x * HID);
        const float2 g1 = *(const float2*)(hbase + (size_t)p1.x * HID);
        const float2 g2 = *(const float2*)(hbase + (size_t)p2.x * HID);
        const float2 g3 = *(const float2*)(hbase + (size_t)p3.x * HID);
        const float q0 = __int_as_float(p0.y);
        const float q1 = __int_as_float(p1.y);
        const float q2 = __int_as_float(p2.y);
        const float q3 = __int_as_float(p3.y);
        acc.x = fmaf(q0, g0.x, acc.x); acc.y = fmaf(q0, g0.y, acc.y);
        acc.x = fmaf(q1, g1.x, acc.x); acc.y = fmaf(q1, g1.y, acc.y);
        acc.x = fmaf(q2, g2.x, acc.x); acc.y = fmaf(q2, g2.y, acc.y);
        acc.x = fmaf(q3, g3.x, acc.x); acc.y = fmaf(q3, g3.y, acc.y);
    }
    for (; i < e; ++i) {
        const int2 p = cw[i];
        const float q = __int_as_float(p.y);
        const float2 g = *(const float2*)(hbase + (size_t)p.x * HID);
        acc.x = fmaf(q, g.x, acc.x);
        acc.y = fmaf(q, g.y, acc.y);
    }

    if (storeH)
        *(float2*)(hout + (size_t)wid * HID + lane * 2) = acc;

    // fused projection: z[wid] += fw * (acc_row @ Wout)
    const float fw = fwp[0];
    float zadd = 0.f;
#pragma unroll
    for (int c = 0; c < COUT; ++c) {
        float pp = fmaf(acc.x, w0[c], acc.y * w1[c]);
#pragma unroll
        for (int off = 32; off; off >>= 1) pp += __shfl_xor(pp, off);
        if (lane == c) zadd = pp;
    }
    if (lane < COUT) {
        const size_t o = (size_t)wid * COUT + lane;
        z[o] += fw * zadd;
    }
}

// ---------------- z (+)= fw * (h @ Wout_branch) (+ b_out on init) ----------------
__global__ __launch_bounds__(256) void zacc_kernel(
    const float* __restrict__ h, const float* __restrict__ Wout,
    const float* __restrict__ bout, float* __restrict__ z,
    const float* __restrict__ fwp, int initf, int n)
{
    const int wid = (blockIdx.x * blockDim.x + threadIdx.x) >> 6;
    if (wid >= n) return;
    const int lane = threadIdx.x & 63;
    const float2 hv = *(const float2*)(h + (size_t)wid * HID + lane * 2);
    const int f0 = lane * 2;
    const float fw = fwp[0];
    float val = 0.f;
#pragma unroll
    for (int c = 0; c < COUT; ++c) {
        float pp = fmaf(hv.x, Wout[f0 * COUT + c], hv.y * Wout[(f0 + 1) * COUT + c]);
#pragma unroll
        for (int off = 32; off; off >>= 1) pp += __shfl_xor(pp, off);
        if (lane == c) val = pp;
    }
    if (lane < COUT) {
        const size_t o = (size_t)wid * COUT + lane;
        if (initf) z[o] = fw * val + bout[lane];
        else z[o] += fw * val;
    }
}

// ---------------- log_softmax in place ----------------
__global__ void logsm_kernel(float* __restrict__ z, int n)
{
    const int r = blockIdx.x * blockDim.x + threadIdx.x;
    if (r >= n) return;
    float v[COUT];
    float m = -1e30f;
#pragma unroll
    for (int c = 0; c < COUT; ++c) { v[c] = z[(size_t)r * COUT + c]; m = fmaxf(m, v[c]); }
    float s = 0.f;
#pragma unroll
    for (int c = 0; c < COUT; ++c) s += expf(v[c] - m);
    const float l = logf(s) + m;
#pragma unroll
    for (int c = 0; c < COUT; ++c) z[(size_t)r * COUT + c] = v[c] - l;
}

extern "C" void kernel_launch(void* const* d_in, const int* in_sizes, int n_in,
                              void* d_out, int out_size, void* d_ws, size_t ws_size,
                              hipStream_t stream)
{
    const float* x    = (const float*)d_in[0];
    const int*   ei1  = (const int*)d_in[1];
    const float* ew1  = (const float*)d_in[2];
    const int*   ei2  = (const int*)d_in[3];
    const float* ew2  = (const float*)d_in[4];
    const float* Win  = (const float*)d_in[5];
    const float* bin  = (const float*)d_in[6];
    const float* fW   = (const float*)d_in[7];
    const float* Wout = (const float*)d_in[8];
    const float* bout = (const float*)d_in[9];
    const int n  = in_sizes[0] / F_IN;
    const int E1 = in_sizes[2];
    const int E2 = in_sizes[4];
    const int Emax = E1 > E2 ? E1 : E2;
    float* z = (float*)d_out;

    char* p = (char*)d_ws;
    auto alloc = [&](size_t bytes) { char* r = p; p += (bytes + 255) & ~(size_t)255; return r; };
    float* hA   = (float*)alloc((size_t)n * HID * 4);
    float* hB   = (float*)alloc((size_t)n * HID * 4);
    int*   cnt  = (int*)alloc((size_t)n * 4);
    int*   rowp = (int*)alloc((size_t)(n + 1) * 4);
    int*   pos  = (int*)alloc((size_t)n * 4);
    int2*  cw   = (int2*)alloc((size_t)Emax * 8);

    const int rowBlocks = (n + 3) / 4;   // 4 waves (rows) per 256-thread block

    for (int br = 0; br < 2; ++br) {
        const int*   ei  = br ? ei2 : ei1;
        const float* ew  = br ? ew2 : ew1;
        const int    E   = br ? E2 : E1;
        const float* fwb = fW + (size_t)br * (KHOPS + 1);
        const float* Wob = Wout + (size_t)br * HID * COUT;

        hipMemsetAsync(cnt, 0, (size_t)n * 4, stream);
        hipLaunchKernelGGL(hist_kernel, dim3(1024), dim3(256), 0, stream, ei, E, cnt);
        hipLaunchKernelGGL(scan_kernel, dim3(1), dim3(256), 0, stream, cnt, rowp, pos, n);
        hipLaunchKernelGGL(scatter_kernel, dim3(1024), dim3(256), 0, stream,
                           ei, ei + E, ew, E, pos, cw);

        hipLaunchKernelGGL(gemm_in_kernel, dim3((n + BM - 1) / BM), dim3(256), 0, stream,
                           x, Win + (size_t)br * F_IN * HID, bin + (size_t)br * HID, hA, n);

        // z (init/acc) with fw0 * h0 contribution
        hipLaunchKernelGGL(zacc_kernel, dim3(rowBlocks), dim3(256), 0, stream,
                           hA, Wob, bout, z, fwb, br == 0 ? 1 : 0, n);

        float* cur = hA; float* nxt = hB;
        for (int k = 0; k < KHOPS; ++k) {
            const int storeH = (k < KHOPS - 1) ? 1 : 0;
            hipLaunchKernelGGL(spmm_kernel, dim3(rowBlocks), dim3(256), 0, stream,
                               rowp, cw, cur, nxt, Wob, z, fwb + k + 1, storeH, n);
            float* tmp = cur; cur = nxt; nxt = tmp;
        }
    }
    hipLaunchKernelGGL(logsm_kernel, dim3((n + 255) / 256), dim3(256), 0, stream, z, n);
}

// Round 3
// 4534.019 us; speedup vs baseline: 1.6949x; 1.3200x over previous
//
#include <hip/hip_runtime.h>

#define F_IN 512
#define HID 128
#define KHOPS 10
#define COUT 10
#define BM 64
#define BK 16

typedef unsigned int uint;

__device__ __forceinline__ uint f2bf1(float f) {
    uint u = __float_as_uint(f);
    return (u + 0x7fffu + ((u >> 16) & 1u)) >> 16;   // RNE
}
__device__ __forceinline__ uint packbf(float a, float b) {
    return f2bf1(a) | (f2bf1(b) << 16);
}
__device__ __forceinline__ float bflo(uint u) { return __uint_as_float(u << 16); }
__device__ __forceinline__ float bfhi(uint u) { return __uint_as_float(u & 0xffff0000u); }

// ---------------- GEMM: h = bf16(x @ W + b), both branches via blockIdx.y ----------------
__global__ __launch_bounds__(256) void gemm_in_kernel(
    const float* __restrict__ x, const float* __restrict__ Win,
    const float* __restrict__ bin, uint* __restrict__ h1, uint* __restrict__ h2, int n)
{
    const int br = blockIdx.y;
    const float* W = Win + (size_t)br * F_IN * HID;
    const float* bias = bin + (size_t)br * HID;
    uint* h = br ? h2 : h1;

    __shared__ float xs[BM][BK + 1];
    __shared__ float wsb[BK][HID];
    const int t = threadIdx.x;
    const int row0 = blockIdx.x * BM;
    const int ty = t >> 4, tx = t & 15;

    float acc[4][8];
#pragma unroll
    for (int i = 0; i < 4; ++i)
#pragma unroll
        for (int j = 0; j < 8; ++j) acc[i][j] = 0.f;

    const int xr = t >> 2;
    const int xk = (t & 3) * 4;

    for (int k0 = 0; k0 < F_IN; k0 += BK) {
        float4 xv = make_float4(0.f, 0.f, 0.f, 0.f);
        if (row0 + xr < n)
            xv = *(const float4*)(x + (size_t)(row0 + xr) * F_IN + k0 + xk);
        xs[xr][xk] = xv.x; xs[xr][xk + 1] = xv.y;
        xs[xr][xk + 2] = xv.z; xs[xr][xk + 3] = xv.w;
#pragma unroll
        for (int rep = 0; rep < 2; ++rep) {
            int idx = t + rep * 256;
            int kr = idx >> 5;
            int c4 = (idx & 31) * 4;
            *(float4*)(&wsb[kr][c4]) = *(const float4*)(W + (size_t)(k0 + kr) * HID + c4);
        }
        __syncthreads();
#pragma unroll
        for (int kk = 0; kk < BK; ++kk) {
            float a0 = xs[ty * 4 + 0][kk];
            float a1 = xs[ty * 4 + 1][kk];
            float a2 = xs[ty * 4 + 2][kk];
            float a3 = xs[ty * 4 + 3][kk];
            const float4 b0 = *(const float4*)(&wsb[kk][tx * 8]);
            const float4 b1 = *(const float4*)(&wsb[kk][tx * 8 + 4]);
            acc[0][0] = fmaf(a0, b0.x, acc[0][0]); acc[0][1] = fmaf(a0, b0.y, acc[0][1]);
            acc[0][2] = fmaf(a0, b0.z, acc[0][2]); acc[0][3] = fmaf(a0, b0.w, acc[0][3]);
            acc[0][4] = fmaf(a0, b1.x, acc[0][4]); acc[0][5] = fmaf(a0, b1.y, acc[0][5]);
            acc[0][6] = fmaf(a0, b1.z, acc[0][6]); acc[0][7] = fmaf(a0, b1.w, acc[0][7]);
            acc[1][0] = fmaf(a1, b0.x, acc[1][0]); acc[1][1] = fmaf(a1, b0.y, acc[1][1]);
            acc[1][2] = fmaf(a1, b0.z, acc[1][2]); acc[1][3] = fmaf(a1, b0.w, acc[1][3]);
            acc[1][4] = fmaf(a1, b1.x, acc[1][4]); acc[1][5] = fmaf(a1, b1.y, acc[1][5]);
            acc[1][6] = fmaf(a1, b1.z, acc[1][6]); acc[1][7] = fmaf(a1, b1.w, acc[1][7]);
            acc[2][0] = fmaf(a2, b0.x, acc[2][0]); acc[2][1] = fmaf(a2, b0.y, acc[2][1]);
            acc[2][2] = fmaf(a2, b0.z, acc[2][2]); acc[2][3] = fmaf(a2, b0.w, acc[2][3]);
            acc[2][4] = fmaf(a2, b1.x, acc[2][4]); acc[2][5] = fmaf(a2, b1.y, acc[2][5]);
            acc[2][6] = fmaf(a2, b1.z, acc[2][6]); acc[2][7] = fmaf(a2, b1.w, acc[2][7]);
            acc[3][0] = fmaf(a3, b0.x, acc[3][0]); acc[3][1] = fmaf(a3, b0.y, acc[3][1]);
            acc[3][2] = fmaf(a3, b0.z, acc[3][2]); acc[3][3] = fmaf(a3, b0.w, acc[3][3]);
            acc[3][4] = fmaf(a3, b1.x, acc[3][4]); acc[3][5] = fmaf(a3, b1.y, acc[3][5]);
            acc[3][6] = fmaf(a3, b1.z, acc[3][6]); acc[3][7] = fmaf(a3, b1.w, acc[3][7]);
        }
        __syncthreads();
    }

    const float4 bv0 = *(const float4*)(bias + tx * 8);
    const float4 bv1 = *(const float4*)(bias + tx * 8 + 4);
#pragma unroll
    for (int i = 0; i < 4; ++i) {
        int row = row0 + ty * 4 + i;
        if (row >= n) continue;
        uint4 o;
        o.x = packbf(acc[i][0] + bv0.x, acc[i][1] + bv0.y);
        o.y = packbf(acc[i][2] + bv0.z, acc[i][3] + bv0.w);
        o.z = packbf(acc[i][4] + bv1.x, acc[i][5] + bv1.y);
        o.w = packbf(acc[i][6] + bv1.z, acc[i][7] + bv1.w);
        *(uint4*)(h + (size_t)row * 64 + tx * 4) = o;
    }
}

// ---------------- CSR build: bucket (row>>6) then in-LDS counting sort ----------------
__global__ void bhist_kernel(const int* __restrict__ rows, int E, int* __restrict__ bcnt, int nb)
{
    extern __shared__ int sh[];
    for (int i = threadIdx.x; i < nb; i += blockDim.x) sh[i] = 0;
    __syncthreads();
    for (int i = blockIdx.x * blockDim.x + threadIdx.x; i < E; i += gridDim.x * blockDim.x)
        atomicAdd(&sh[rows[i] >> 6], 1);
    __syncthreads();
    for (int i = threadIdx.x; i < nb; i += blockDim.x)
        if (sh[i]) atomicAdd(&bcnt[i], sh[i]);
}

__global__ __launch_bounds__(256) void bscan_kernel(
    const int* __restrict__ bcnt, int* __restrict__ bbase, int* __restrict__ bcur,
    int* __restrict__ rowp, int nb, int n, int E)
{
    __shared__ int ssum[256];
    const int t = threadIdx.x;
    const int chunk = (nb + 255) / 256;
    const int start = t * chunk;
    const int end = (start + chunk < nb) ? start + chunk : nb;
    int sum = 0;
    for (int i = start; i < end; ++i) sum += bcnt[i];
    ssum[t] = sum;
    __syncthreads();
    if (t == 0) {
        int run = 0;
        for (int i = 0; i < 256; ++i) { int v = ssum[i]; ssum[i] = run; run += v; }
        bbase[nb] = E;
        rowp[n] = E;
    }
    __syncthreads();
    int run = ssum[t];
    for (int i = start; i < end; ++i) {
        bbase[i] = run; bcur[i] = run; run += bcnt[i];
    }
}

__global__ void bscatter_kernel(const int* __restrict__ rows, const int* __restrict__ cols,
                                const float* __restrict__ w, int E, int* __restrict__ bcur,
                                int* __restrict__ tRow, int2* __restrict__ tCW)
{
    for (int i = blockIdx.x * blockDim.x + threadIdx.x; i < E; i += gridDim.x * blockDim.x) {
        int r = rows[i];
        int p = atomicAdd(&bcur[r >> 6], 1);
        tRow[p] = r;
        tCW[p] = make_int2(cols[i], __float_as_int(w[i]));
    }
}

__global__ __launch_bounds__(256) void bsort_kernel(
    const int* __restrict__ bbase, const int* __restrict__ tRow, const int2* __restrict__ tCW,
    int* __restrict__ rowp, int2* __restrict__ cw, int n)
{
    __shared__ int cnt[64], soff[64], pos[64];
    const int b = blockIdx.x;
    const int t = threadIdx.x;
    const int base = bbase[b];
    const int m = bbase[b + 1] - base;
    if (t < 64) cnt[t] = 0;
    __syncthreads();
    for (int i = t; i < m; i += 256) atomicAdd(&cnt[tRow[base + i] & 63], 1);
    __syncthreads();
    if (t == 0) {
        int run = 0;
#pragma unroll
        for (int r = 0; r < 64; ++r) { soff[r] = run; run += cnt[r]; }
    }
    __syncthreads();
    if (t < 64) {
        pos[t] = soff[t];
        int g = b * 64 + t;
        if (g < n) rowp[g] = base + soff[t];
    }
    __syncthreads();
    for (int i = t; i < m; i += 256) {
        int2 e = tCW[base + i];
        int r = tRow[base + i] & 63;
        int p = atomicAdd(&pos[r], 1);
        cw[base + p] = e;
    }
}

// ---------------- SpMM (bf16 gather, fp32 acc) + fused z2 accumulation, both branches ----------------
struct BrArgs {
    const int* rowp;
    const int2* cw;
    const uint* hin;
    uint* hout;
    const float* Wo;
};

__global__ __launch_bounds__(256) void spmm2_kernel(
    BrArgs A, BrArgs B, const float* __restrict__ fW, int k,
    float* __restrict__ z2, int storeH, int n)
{
    const int wid = (blockIdx.x * blockDim.x + threadIdx.x) >> 6;
    if (wid >= n) return;
    const int br = blockIdx.y;
    const int*   rowp = br ? B.rowp : A.rowp;
    const int2*  cw   = br ? B.cw   : A.cw;
    const uint*  hin  = br ? B.hin  : A.hin;
    uint*        hout = br ? B.hout : A.hout;
    const float* Wo   = br ? B.Wo   : A.Wo;
    const int lane = threadIdx.x & 63;

    float w0[COUT], w1[COUT];
    const float* wp = Wo + (size_t)(lane * 2) * COUT;
#pragma unroll
    for (int c = 0; c < COUT; ++c) { w0[c] = wp[c]; w1[c] = wp[COUT + c]; }

    const int s = rowp[wid];
    const int e = rowp[wid + 1];
    const uint* hb = hin + lane;

    float2 acc = make_float2(0.f, 0.f);
    int i = s;
    const int e8 = s + ((e - s) & ~7);
    for (; i < e8; i += 8) {
        const int2 p0 = cw[i];     const int2 p1 = cw[i + 1];
        const int2 p2 = cw[i + 2]; const int2 p3 = cw[i + 3];
        const int2 p4 = cw[i + 4]; const int2 p5 = cw[i + 5];
        const int2 p6 = cw[i + 6]; const int2 p7 = cw[i + 7];
        const uint g0 = hb[(size_t)p0.x * 64];
        const uint g1 = hb[(size_t)p1.x * 64];
        const uint g2 = hb[(size_t)p2.x * 64];
        const uint g3 = hb[(size_t)p3.x * 64];
        const uint g4 = hb[(size_t)p4.x * 64];
        const uint g5 = hb[(size_t)p5.x * 64];
        const uint g6 = hb[(size_t)p6.x * 64];
        const uint g7 = hb[(size_t)p7.x * 64];
        const float q0 = __int_as_float(p0.y), q1 = __int_as_float(p1.y);
        const float q2 = __int_as_float(p2.y), q3 = __int_as_float(p3.y);
        const float q4 = __int_as_float(p4.y), q5 = __int_as_float(p5.y);
        const float q6 = __int_as_float(p6.y), q7 = __int_as_float(p7.y);
        acc.x = fmaf(q0, bflo(g0), acc.x); acc.y = fmaf(q0, bfhi(g0), acc.y);
        acc.x = fmaf(q1, bflo(g1), acc.x); acc.y = fmaf(q1, bfhi(g1), acc.y);
        acc.x = fmaf(q2, bflo(g2), acc.x); acc.y = fmaf(q2, bfhi(g2), acc.y);
        acc.x = fmaf(q3, bflo(g3), acc.x); acc.y = fmaf(q3, bfhi(g3), acc.y);
        acc.x = fmaf(q4, bflo(g4), acc.x); acc.y = fmaf(q4, bfhi(g4), acc.y);
        acc.x = fmaf(q5, bflo(g5), acc.x); acc.y = fmaf(q5, bfhi(g5), acc.y);
        acc.x = fmaf(q6, bflo(g6), acc.x); acc.y = fmaf(q6, bfhi(g6), acc.y);
        acc.x = fmaf(q7, bflo(g7), acc.x); acc.y = fmaf(q7, bfhi(g7), acc.y);
    }
    for (; i < e; ++i) {
        const int2 p = cw[i];
        const float q = __int_as_float(p.y);
        const uint g = hb[(size_t)p.x * 64];
        acc.x = fmaf(q, bflo(g), acc.x);
        acc.y = fmaf(q, bfhi(g), acc.y);
    }

    if (storeH)
        hout[(size_t)wid * 64 + lane] = packbf(acc.x, acc.y);

    const float fw = fW[br * (KHOPS + 1) + k + 1];
    float zadd = 0.f;
#pragma unroll
    for (int c = 0; c < COUT; ++c) {
        float pp = fmaf(acc.x, w0[c], acc.y * w1[c]);
#pragma unroll
        for (int off = 32; off; off >>= 1) pp += __shfl_xor(pp, off);
        if (lane == c) zadd = pp;
    }
    if (lane < COUT) {
        const size_t o = (size_t)wid * (2 * COUT) + br * COUT + lane;
        z2[o] += fw * zadd;
    }
}

// ---------------- z2 init: fw0 * (h0 @ Wout) per branch ----------------
__global__ __launch_bounds__(256) void zacc2_kernel(
    const uint* __restrict__ h1, const uint* __restrict__ h2,
    const float* __restrict__ Wout, const float* __restrict__ fW,
    float* __restrict__ z2, int n)
{
    const int wid = (blockIdx.x * blockDim.x + threadIdx.x) >> 6;
    if (wid >= n) return;
    const int lane = threadIdx.x & 63;
    const uint u1 = h1[(size_t)wid * 64 + lane];
    const uint u2 = h2[(size_t)wid * 64 + lane];
    const float a1 = bflo(u1), b1v = bfhi(u1);
    const float a2 = bflo(u2), b2v = bfhi(u2);
    const float* wp1 = Wout + (size_t)(lane * 2) * COUT;
    const float* wp2 = Wout + (size_t)HID * COUT + (size_t)(lane * 2) * COUT;
    float zv1 = 0.f, zv2 = 0.f;
#pragma unroll
    for (int c = 0; c < COUT; ++c) {
        float p1 = fmaf(a1, wp1[c], b1v * wp1[COUT + c]);
        float p2 = fmaf(a2, wp2[c], b2v * wp2[COUT + c]);
#pragma unroll
        for (int off = 32; off; off >>= 1) { p1 += __shfl_xor(p1, off); p2 += __shfl_xor(p2, off); }
        if (lane == c) { zv1 = p1; zv2 = p2; }
    }
    if (lane < COUT) {
        z2[(size_t)wid * (2 * COUT) + lane]        = fW[0] * zv1;
        z2[(size_t)wid * (2 * COUT) + COUT + lane] = fW[KHOPS + 1] * zv2;
    }
}

// ---------------- log_softmax(z2_br0 + z2_br1 + bias) ----------------
__global__ void logsm_kernel(const float* __restrict__ z2, const float* __restrict__ bout,
                             float* __restrict__ out, int n)
{
    const int r = blockIdx.x * blockDim.x + threadIdx.x;
    if (r >= n) return;
    float v[COUT];
    float m = -1e30f;
#pragma unroll
    for (int c = 0; c < COUT; ++c) {
        v[c] = z2[(size_t)r * (2 * COUT) + c] + z2[(size_t)r * (2 * COUT) + COUT + c] + bout[c];
        m = fmaxf(m, v[c]);
    }
    float s = 0.f;
#pragma unroll
    for (int c = 0; c < COUT; ++c) s += expf(v[c] - m);
    const float l = logf(s) + m;
#pragma unroll
    for (int c = 0; c < COUT; ++c) out[(size_t)r * COUT + c] = v[c] - l;
}

extern "C" void kernel_launch(void* const* d_in, const int* in_sizes, int n_in,
                              void* d_out, int out_size, void* d_ws, size_t ws_size,
                              hipStream_t stream)
{
    const float* x    = (const float*)d_in[0];
    const int*   ei1  = (const int*)d_in[1];
    const float* ew1  = (const float*)d_in[2];
    const int*   ei2  = (const int*)d_in[3];
    const float* ew2  = (const float*)d_in[4];
    const float* Win  = (const float*)d_in[5];
    const float* bin  = (const float*)d_in[6];
    const float* fW   = (const float*)d_in[7];
    const float* Wout = (const float*)d_in[8];
    const float* bout = (const float*)d_in[9];
    const int n  = in_sizes[0] / F_IN;
    const int E1 = in_sizes[2];
    const int E2 = in_sizes[4];
    const int Emax = E1 > E2 ? E1 : E2;
    const int nb = (n + 63) / 64;
    float* zout = (float*)d_out;

    char* p = (char*)d_ws;
    auto alloc = [&](size_t bytes) { char* r = p; p += (bytes + 255) & ~(size_t)255; return r; };
    // region A: 4 bf16 h buffers; CSR-build temps alias the front of it (build precedes gemm)
    char* regA = alloc((size_t)4 * n * 64 * 4);
    uint* h1A = (uint*)regA;
    uint* h1B = (uint*)(regA + (size_t)n * 64 * 4);
    uint* h2A = (uint*)(regA + (size_t)2 * n * 64 * 4);
    uint* h2B = (uint*)(regA + (size_t)3 * n * 64 * 4);
    int*  tRow = (int*)regA;                                  // Emax*4  (12.8 MB)
    int2* tCW  = (int2*)(regA + (((size_t)Emax * 4 + 255) & ~(size_t)255)); // Emax*8
    int2* cw1  = (int2*)alloc((size_t)Emax * 8);
    int2* cw2  = (int2*)alloc((size_t)Emax * 8);
    int*  rowp1 = (int*)alloc((size_t)(n + 1) * 4);
    int*  rowp2 = (int*)alloc((size_t)(n + 1) * 4);
    float* z2  = (float*)alloc((size_t)n * 2 * COUT * 4);
    int*  bcnt  = (int*)alloc((size_t)nb * 4);
    int*  bbase = (int*)alloc((size_t)(nb + 1) * 4);
    int*  bcur  = (int*)alloc((size_t)nb * 4);

    const int rowBlocks = (n + 3) / 4;

    // CSR build for both branches (uses temp region, before gemm writes h)
    for (int br = 0; br < 2; ++br) {
        const int*   ei = br ? ei2 : ei1;
        const float* ew = br ? ew2 : ew1;
        const int    E  = br ? E2 : E1;
        int*  rowp = br ? rowp2 : rowp1;
        int2* cw   = br ? cw2 : cw1;
        hipMemsetAsync(bcnt, 0, (size_t)nb * 4, stream);
        hipLaunchKernelGGL(bhist_kernel, dim3(256), dim3(256), nb * 4, stream, ei, E, bcnt, nb);
        hipLaunchKernelGGL(bscan_kernel, dim3(1), dim3(256), 0, stream,
                           bcnt, bbase, bcur, rowp, nb, n, E);
        hipLaunchKernelGGL(bscatter_kernel, dim3(1024), dim3(256), 0, stream,
                           ei, ei + E, ew, E, bcur, tRow, tCW);
        hipLaunchKernelGGL(bsort_kernel, dim3(nb), dim3(256), 0, stream,
                           bbase, tRow, tCW, rowp, cw, n);
    }

    // h0 for both branches
    hipLaunchKernelGGL(gemm_in_kernel, dim3((n + BM - 1) / BM, 2), dim3(256), 0, stream,
                       x, Win, bin, h1A, h2A, n);

    // z2 init with fw0 * h0 projections
    hipLaunchKernelGGL(zacc2_kernel, dim3(rowBlocks), dim3(256), 0, stream,
                       h1A, h2A, Wout, fW, z2, n);

    uint* cur1 = h1A; uint* nxt1 = h1B;
    uint* cur2 = h2A; uint* nxt2 = h2B;
    for (int k = 0; k < KHOPS; ++k) {
        const int storeH = (k < KHOPS - 1) ? 1 : 0;
        BrArgs A { rowp1, cw1, cur1, nxt1, Wout };
        BrArgs B { rowp2, cw2, cur2, nxt2, Wout + (size_t)HID * COUT };
        hipLaunchKernelGGL(spmm2_kernel, dim3(rowBlocks, 2), dim3(256), 0, stream,
                           A, B, fW, k, z2, storeH, n);
        uint* t1 = cur1; cur1 = nxt1; nxt1 = t1;
        uint* t2 = cur2; cur2 = nxt2; nxt2 = t2;
    }

    hipLaunchKernelGGL(logsm_kernel, dim3((n + 255) / 256), dim3(256), 0, stream,
                       z2, bout, zout, n);
}

// Round 4
// 2958.794 us; speedup vs baseline: 2.5972x; 1.5324x over previous
//
#include <hip/hip_runtime.h>

#define F_IN 512
#define HID 128
#define KHOPS 10
#define COUT 10
#define BM 64
#define BK 16
#define COLMASK 0x1FFFF   // n <= 131072

typedef unsigned int uint;

__device__ __forceinline__ uint f2bf1(float f) {
    uint u = __float_as_uint(f);
    return (u + 0x7fffu + ((u >> 16) & 1u)) >> 16;   // RNE
}
__device__ __forceinline__ uint packbf(float a, float b) {
    return f2bf1(a) | (f2bf1(b) << 16);
}
__device__ __forceinline__ float bflo(uint u) { return __uint_as_float(u << 16); }
__device__ __forceinline__ float bfhi(uint u) { return __uint_as_float(u & 0xffff0000u); }

// ---------------- GEMM: h = bf16(x @ W + b), both branches via blockIdx.y ----------------
__global__ __launch_bounds__(256) void gemm_in_kernel(
    const float* __restrict__ x, const float* __restrict__ Win,
    const float* __restrict__ bin, uint* __restrict__ h1, uint* __restrict__ h2, int n)
{
    const int br = blockIdx.y;
    const float* W = Win + (size_t)br * F_IN * HID;
    const float* bias = bin + (size_t)br * HID;
    uint* h = br ? h2 : h1;

    __shared__ float xs[BM][BK + 1];
    __shared__ float wsb[BK][HID];
    const int t = threadIdx.x;
    const int row0 = blockIdx.x * BM;
    const int ty = t >> 4, tx = t & 15;

    float acc[4][8];
#pragma unroll
    for (int i = 0; i < 4; ++i)
#pragma unroll
        for (int j = 0; j < 8; ++j) acc[i][j] = 0.f;

    const int xr = t >> 2;
    const int xk = (t & 3) * 4;

    for (int k0 = 0; k0 < F_IN; k0 += BK) {
        float4 xv = make_float4(0.f, 0.f, 0.f, 0.f);
        if (row0 + xr < n)
            xv = *(const float4*)(x + (size_t)(row0 + xr) * F_IN + k0 + xk);
        xs[xr][xk] = xv.x; xs[xr][xk + 1] = xv.y;
        xs[xr][xk + 2] = xv.z; xs[xr][xk + 3] = xv.w;
#pragma unroll
        for (int rep = 0; rep < 2; ++rep) {
            int idx = t + rep * 256;
            int kr = idx >> 5;
            int c4 = (idx & 31) * 4;
            *(float4*)(&wsb[kr][c4]) = *(const float4*)(W + (size_t)(k0 + kr) * HID + c4);
        }
        __syncthreads();
#pragma unroll
        for (int kk = 0; kk < BK; ++kk) {
            float a0 = xs[ty * 4 + 0][kk];
            float a1 = xs[ty * 4 + 1][kk];
            float a2 = xs[ty * 4 + 2][kk];
            float a3 = xs[ty * 4 + 3][kk];
            const float4 b0 = *(const float4*)(&wsb[kk][tx * 8]);
            const float4 b1 = *(const float4*)(&wsb[kk][tx * 8 + 4]);
            acc[0][0] = fmaf(a0, b0.x, acc[0][0]); acc[0][1] = fmaf(a0, b0.y, acc[0][1]);
            acc[0][2] = fmaf(a0, b0.z, acc[0][2]); acc[0][3] = fmaf(a0, b0.w, acc[0][3]);
            acc[0][4] = fmaf(a0, b1.x, acc[0][4]); acc[0][5] = fmaf(a0, b1.y, acc[0][5]);
            acc[0][6] = fmaf(a0, b1.z, acc[0][6]); acc[0][7] = fmaf(a0, b1.w, acc[0][7]);
            acc[1][0] = fmaf(a1, b0.x, acc[1][0]); acc[1][1] = fmaf(a1, b0.y, acc[1][1]);
            acc[1][2] = fmaf(a1, b0.z, acc[1][2]); acc[1][3] = fmaf(a1, b0.w, acc[1][3]);
            acc[1][4] = fmaf(a1, b1.x, acc[1][4]); acc[1][5] = fmaf(a1, b1.y, acc[1][5]);
            acc[1][6] = fmaf(a1, b1.z, acc[1][6]); acc[1][7] = fmaf(a1, b1.w, acc[1][7]);
            acc[2][0] = fmaf(a2, b0.x, acc[2][0]); acc[2][1] = fmaf(a2, b0.y, acc[2][1]);
            acc[2][2] = fmaf(a2, b0.z, acc[2][2]); acc[2][3] = fmaf(a2, b0.w, acc[2][3]);
            acc[2][4] = fmaf(a2, b1.x, acc[2][4]); acc[2][5] = fmaf(a2, b1.y, acc[2][5]);
            acc[2][6] = fmaf(a2, b1.z, acc[2][6]); acc[2][7] = fmaf(a2, b1.w, acc[2][7]);
            acc[3][0] = fmaf(a3, b0.x, acc[3][0]); acc[3][1] = fmaf(a3, b0.y, acc[3][1]);
            acc[3][2] = fmaf(a3, b0.z, acc[3][2]); acc[3][3] = fmaf(a3, b0.w, acc[3][3]);
            acc[3][4] = fmaf(a3, b1.x, acc[3][4]); acc[3][5] = fmaf(a3, b1.y, acc[3][5]);
            acc[3][6] = fmaf(a3, b1.z, acc[3][6]); acc[3][7] = fmaf(a3, b1.w, acc[3][7]);
        }
        __syncthreads();
    }

    const float4 bv0 = *(const float4*)(bias + tx * 8);
    const float4 bv1 = *(const float4*)(bias + tx * 8 + 4);
#pragma unroll
    for (int i = 0; i < 4; ++i) {
        int row = row0 + ty * 4 + i;
        if (row >= n) continue;
        uint4 o;
        o.x = packbf(acc[i][0] + bv0.x, acc[i][1] + bv0.y);
        o.y = packbf(acc[i][2] + bv0.z, acc[i][3] + bv0.w);
        o.z = packbf(acc[i][4] + bv1.x, acc[i][5] + bv1.y);
        o.w = packbf(acc[i][6] + bv1.z, acc[i][7] + bv1.w);
        *(uint4*)(h + (size_t)row * 64 + tx * 4) = o;
    }
}

// ---------------- CSR build ----------------
// bucket = row >> 6 (64 rows per bucket). Packed edge record: lo = col | (rowlocal<<17), hi = w bits.

__global__ void bhist_kernel(const int* __restrict__ r1, int E1,
                             const int* __restrict__ r2, int E2,
                             int* __restrict__ bcnt, int nb)
{
    extern __shared__ int sh[];
    const int br = blockIdx.y;
    const int* rows = br ? r2 : r1;
    const int E = br ? E2 : E1;
    int* bc = bcnt + (size_t)br * nb;
    for (int i = threadIdx.x; i < nb; i += blockDim.x) sh[i] = 0;
    __syncthreads();
    for (int i = blockIdx.x * blockDim.x + threadIdx.x; i < E; i += gridDim.x * blockDim.x)
        atomicAdd(&sh[rows[i] >> 6], 1);
    __syncthreads();
    for (int i = threadIdx.x; i < nb; i += blockDim.x)
        if (sh[i]) atomicAdd(&bc[i], sh[i]);
}

__global__ __launch_bounds__(256) void bscan_kernel(
    const int* __restrict__ bcnt, int* __restrict__ bbase, int* __restrict__ bcur,
    int* __restrict__ rowp1, int* __restrict__ rowp2,
    int nb, int n, int E1, int E2)
{
    __shared__ int ssum[256];
    const int br = blockIdx.y;
    const int* bc = bcnt + (size_t)br * nb;
    int* bb = bbase + (size_t)br * (nb + 1);
    int* cur = bcur + (size_t)br * nb;
    int* rowp = br ? rowp2 : rowp1;
    const int E = br ? E2 : E1;
    const int t = threadIdx.x;
    const int chunk = (nb + 255) / 256;
    const int start = t * chunk;
    const int end = (start + chunk < nb) ? start + chunk : nb;
    int sum = 0;
    for (int i = start; i < end; ++i) sum += bc[i];
    ssum[t] = sum;
    __syncthreads();
    if (t == 0) {
        int run = 0;
        for (int i = 0; i < 256; ++i) { int v = ssum[i]; ssum[i] = run; run += v; }
        bb[nb] = E;
        rowp[n] = E;
    }
    __syncthreads();
    int run = ssum[t];
    for (int i = start; i < end; ++i) {
        bb[i] = run; cur[i] = run; run += bc[i];
    }
}

// block-aggregated bucket scatter: per-block LDS histogram -> one range-reserve atomic
// per (block,bucket) -> contiguous packed writes
#define SCAT_BLOCKS 256
__global__ __launch_bounds__(256) void bscat_kernel(
    const int* __restrict__ r1, const int* __restrict__ c1, const float* __restrict__ w1, int E1,
    const int* __restrict__ r2, const int* __restrict__ c2, const float* __restrict__ w2, int E2,
    int* __restrict__ bcur, int2* __restrict__ t1, int2* __restrict__ t2, int nb)
{
    extern __shared__ int sh[];
    int* lh = sh;            // hist, then per-bucket running pos
    int* lbase = sh + nb;    // reserved global base per bucket
    const int br = blockIdx.y;
    const int* rows = br ? r2 : r1;
    const int* cols = br ? c2 : c1;
    const float* w  = br ? w2 : w1;
    const int E = br ? E2 : E1;
    int* cur = bcur + (size_t)br * nb;
    int2* tcw = br ? t2 : t1;
    const int t = threadIdx.x;

    for (int i = t; i < nb; i += 256) lh[i] = 0;
    __syncthreads();

    const int per = (E + SCAT_BLOCKS - 1) / SCAT_BLOCKS;
    const int c0 = blockIdx.x * per;
    const int cend = (c0 + per < E) ? c0 + per : E;

    for (int i = c0 + t; i < cend; i += 256)
        atomicAdd(&lh[rows[i] >> 6], 1);
    __syncthreads();
    for (int b = t; b < nb; b += 256) {
        int c = lh[b];
        lbase[b] = c ? atomicAdd(&cur[b], c) : 0;
        lh[b] = 0;
    }
    __syncthreads();
    for (int i = c0 + t; i < cend; i += 256) {
        int r = rows[i];
        int b = r >> 6;
        int p = atomicAdd(&lh[b], 1);
        uint lo = (uint)cols[i] | ((uint)(r & 63) << 17);
        tcw[lbase[b] + p] = make_int2((int)lo, __float_as_int(w[i]));
    }
}

__global__ __launch_bounds__(256) void bsort_kernel(
    const int* __restrict__ bbase,
    const int2* __restrict__ t1, const int2* __restrict__ t2,
    int* __restrict__ rowp1, int* __restrict__ rowp2,
    int2* __restrict__ cw1, int2* __restrict__ cw2, int nb, int n)
{
    __shared__ int cnt[64], soff[64], pos[64];
    const int br = blockIdx.y;
    const int* bb = bbase + (size_t)br * (nb + 1);
    const int2* tcw = br ? t2 : t1;
    int* rowp = br ? rowp2 : rowp1;
    int2* cw = br ? cw2 : cw1;
    const int b = blockIdx.x;
    const int t = threadIdx.x;
    const int base = bb[b];
    const int m = bb[b + 1] - base;
    if (t < 64) cnt[t] = 0;
    __syncthreads();
    for (int i = t; i < m; i += 256) atomicAdd(&cnt[((uint)tcw[base + i].x >> 17) & 63], 1);
    __syncthreads();
    if (t == 0) {
        int run = 0;
#pragma unroll
        for (int r = 0; r < 64; ++r) { soff[r] = run; run += cnt[r]; }
    }
    __syncthreads();
    if (t < 64) {
        pos[t] = soff[t];
        int g = b * 64 + t;
        if (g < n) rowp[g] = base + soff[t];
    }
    __syncthreads();
    for (int i = t; i < m; i += 256) {
        int2 e = tcw[base + i];
        int r = ((uint)e.x >> 17) & 63;
        int p = atomicAdd(&pos[r], 1);
        cw[base + p] = e;
    }
}

// ---------------- SpMM (bf16 gather, readlane edge broadcast) + fused z2 ----------------
struct BrArgs {
    const int* rowp;
    const int2* cw;
    const uint* hin;
    uint* hout;
    const float* Wo;
};

__global__ __launch_bounds__(256) void spmm2_kernel(
    BrArgs A, BrArgs B, const float* __restrict__ fW, int k,
    float* __restrict__ z2, int storeH, int n)
{
    // branch = block parity -> branch 0 on even XCDs, branch 1 on odd (L2 partitioning)
    const int bid = blockIdx.x;
    const int br = bid & 1;
    const int wid = (bid >> 1) * 4 + (threadIdx.x >> 6);
    if (wid >= n) return;
    const int*   rowp = br ? B.rowp : A.rowp;
    const int2*  cw   = br ? B.cw   : A.cw;
    const uint*  hin  = br ? B.hin  : A.hin;
    uint*        hout = br ? B.hout : A.hout;
    const float* Wo   = br ? B.Wo   : A.Wo;
    const int lane = threadIdx.x & 63;

    float w0[COUT], w1[COUT];
    const float* wp = Wo + (size_t)(lane * 2) * COUT;
#pragma unroll
    for (int c = 0; c < COUT; ++c) { w0[c] = wp[c]; w1[c] = wp[COUT + c]; }

    const int s = rowp[wid];
    const int e = rowp[wid + 1];
    const uint* hb = hin + lane;

    float2 acc = make_float2(0.f, 0.f);
    int i = s;
    while (i < e) {
        const int rem = e - i;
        const int cnt = rem < 64 ? rem : 64;
        int2 my = make_int2(0, 0);
        if (lane < cnt) my = cw[i + lane];
        int j = 0;
        for (; j + 3 < cnt; j += 4) {
            const int x0 = __builtin_amdgcn_readlane(my.x, j);
            const int y0 = __builtin_amdgcn_readlane(my.y, j);
            const int x1 = __builtin_amdgcn_readlane(my.x, j + 1);
            const int y1 = __builtin_amdgcn_readlane(my.y, j + 1);
            const int x2 = __builtin_amdgcn_readlane(my.x, j + 2);
            const int y2 = __builtin_amdgcn_readlane(my.y, j + 2);
            const int x3 = __builtin_amdgcn_readlane(my.x, j + 3);
            const int y3 = __builtin_amdgcn_readlane(my.y, j + 3);
            const uint g0 = hb[(size_t)(x0 & COLMASK) * 64];
            const uint g1 = hb[(size_t)(x1 & COLMASK) * 64];
            const uint g2 = hb[(size_t)(x2 & COLMASK) * 64];
            const uint g3 = hb[(size_t)(x3 & COLMASK) * 64];
            const float q0 = __int_as_float(y0), q1 = __int_as_float(y1);
            const float q2 = __int_as_float(y2), q3 = __int_as_float(y3);
            acc.x = fmaf(q0, bflo(g0), acc.x); acc.y = fmaf(q0, bfhi(g0), acc.y);
            acc.x = fmaf(q1, bflo(g1), acc.x); acc.y = fmaf(q1, bfhi(g1), acc.y);
            acc.x = fmaf(q2, bflo(g2), acc.x); acc.y = fmaf(q2, bfhi(g2), acc.y);
            acc.x = fmaf(q3, bflo(g3), acc.x); acc.y = fmaf(q3, bfhi(g3), acc.y);
        }
        for (; j < cnt; ++j) {
            const int xj = __builtin_amdgcn_readlane(my.x, j);
            const int yj = __builtin_amdgcn_readlane(my.y, j);
            const uint g = hb[(size_t)(xj & COLMASK) * 64];
            const float q = __int_as_float(yj);
            acc.x = fmaf(q, bflo(g), acc.x);
            acc.y = fmaf(q, bfhi(g), acc.y);
        }
        i += cnt;
    }

    if (storeH)
        hout[(size_t)wid * 64 + lane] = packbf(acc.x, acc.y);

    const float fw = fW[br * (KHOPS + 1) + k + 1];
    float zadd = 0.f;
#pragma unroll
    for (int c = 0; c < COUT; ++c) {
        float pp = fmaf(acc.x, w0[c], acc.y * w1[c]);
#pragma unroll
        for (int off = 32; off; off >>= 1) pp += __shfl_xor(pp, off);
        if (lane == c) zadd = pp;
    }
    if (lane < COUT) {
        const size_t o = (size_t)wid * (2 * COUT) + br * COUT + lane;
        z2[o] += fw * zadd;
    }
}

// ---------------- z2 init: fw0 * (h0 @ Wout) per branch ----------------
__global__ __launch_bounds__(256) void zacc2_kernel(
    const uint* __restrict__ h1, const uint* __restrict__ h2,
    const float* __restrict__ Wout, const float* __restrict__ fW,
    float* __restrict__ z2, int n)
{
    const int wid = (blockIdx.x * blockDim.x + threadIdx.x) >> 6;
    if (wid >= n) return;
    const int lane = threadIdx.x & 63;
    const uint u1 = h1[(size_t)wid * 64 + lane];
    const uint u2 = h2[(size_t)wid * 64 + lane];
    const float a1 = bflo(u1), b1v = bfhi(u1);
    const float a2 = bflo(u2), b2v = bfhi(u2);
    const float* wp1 = Wout + (size_t)(lane * 2) * COUT;
    const float* wp2 = Wout + (size_t)HID * COUT + (size_t)(lane * 2) * COUT;
    float zv1 = 0.f, zv2 = 0.f;
#pragma unroll
    for (int c = 0; c < COUT; ++c) {
        float p1 = fmaf(a1, wp1[c], b1v * wp1[COUT + c]);
        float p2 = fmaf(a2, wp2[c], b2v * wp2[COUT + c]);
#pragma unroll
        for (int off = 32; off; off >>= 1) { p1 += __shfl_xor(p1, off); p2 += __shfl_xor(p2, off); }
        if (lane == c) { zv1 = p1; zv2 = p2; }
    }
    if (lane < COUT) {
        z2[(size_t)wid * (2 * COUT) + lane]        = fW[0] * zv1;
        z2[(size_t)wid * (2 * COUT) + COUT + lane] = fW[KHOPS + 1] * zv2;
    }
}

// ---------------- log_softmax(z2_br0 + z2_br1 + bias) ----------------
__global__ void logsm_kernel(const float* __restrict__ z2, const float* __restrict__ bout,
                             float* __restrict__ out, int n)
{
    const int r = blockIdx.x * blockDim.x + threadIdx.x;
    if (r >= n) return;
    float v[COUT];
    float m = -1e30f;
#pragma unroll
    for (int c = 0; c < COUT; ++c) {
        v[c] = z2[(size_t)r * (2 * COUT) + c] + z2[(size_t)r * (2 * COUT) + COUT + c] + bout[c];
        m = fmaxf(m, v[c]);
    }
    float s = 0.f;
#pragma unroll
    for (int c = 0; c < COUT; ++c) s += expf(v[c] - m);
    const float l = logf(s) + m;
#pragma unroll
    for (int c = 0; c < COUT; ++c) out[(size_t)r * COUT + c] = v[c] - l;
}

extern "C" void kernel_launch(void* const* d_in, const int* in_sizes, int n_in,
                              void* d_out, int out_size, void* d_ws, size_t ws_size,
                              hipStream_t stream)
{
    const float* x    = (const float*)d_in[0];
    const int*   ei1  = (const int*)d_in[1];
    const float* ew1  = (const float*)d_in[2];
    const int*   ei2  = (const int*)d_in[3];
    const float* ew2  = (const float*)d_in[4];
    const float* Win  = (const float*)d_in[5];
    const float* bin  = (const float*)d_in[6];
    const float* fW   = (const float*)d_in[7];
    const float* Wout = (const float*)d_in[8];
    const float* bout = (const float*)d_in[9];
    const int n  = in_sizes[0] / F_IN;
    const int E1 = in_sizes[2];
    const int E2 = in_sizes[4];
    const int Emax = E1 > E2 ? E1 : E2;
    const int nb = (n + 63) / 64;
    float* zout = (float*)d_out;

    char* p = (char*)d_ws;
    auto alloc = [&](size_t bytes) { char* r = p; p += (bytes + 255) & ~(size_t)255; return r; };
    // region A: 4 bf16 h buffers; tcw temps alias it (CSR build precedes gemm)
    char* regA = alloc((size_t)4 * n * 64 * 4);
    uint* h1A = (uint*)regA;
    uint* h1B = (uint*)(regA + (size_t)n * 64 * 4);
    uint* h2A = (uint*)(regA + (size_t)2 * n * 64 * 4);
    uint* h2B = (uint*)(regA + (size_t)3 * n * 64 * 4);
    int2* tcw1 = (int2*)regA;
    int2* tcw2 = (int2*)(regA + (size_t)Emax * 8);
    int2* cw1  = (int2*)alloc((size_t)Emax * 8);
    int2* cw2  = (int2*)alloc((size_t)Emax * 8);
    int*  rowp1 = (int*)alloc((size_t)(n + 1) * 4);
    int*  rowp2 = (int*)alloc((size_t)(n + 1) * 4);
    float* z2  = (float*)alloc((size_t)n * 2 * COUT * 4);
    int*  bcnt  = (int*)alloc((size_t)2 * nb * 4);
    int*  bbase = (int*)alloc((size_t)2 * (nb + 1) * 4);
    int*  bcur  = (int*)alloc((size_t)2 * nb * 4);

    const int rowBlocks = (n + 3) / 4;

    // ---- CSR build, both branches per dispatch ----
    hipMemsetAsync(bcnt, 0, (size_t)2 * nb * 4, stream);
    hipLaunchKernelGGL(bhist_kernel, dim3(256, 2), dim3(256), nb * 4, stream,
                       ei1, E1, ei2, E2, bcnt, nb);
    hipLaunchKernelGGL(bscan_kernel, dim3(1, 2), dim3(256), 0, stream,
                       bcnt, bbase, bcur, rowp1, rowp2, nb, n, E1, E2);
    hipLaunchKernelGGL(bscat_kernel, dim3(SCAT_BLOCKS, 2), dim3(256), 2 * nb * 4, stream,
                       ei1, ei1 + E1, ew1, E1, ei2, ei2 + E2, ew2, E2,
                       bcur, tcw1, tcw2, nb);
    hipLaunchKernelGGL(bsort_kernel, dim3(nb, 2), dim3(256), 0, stream,
                       bbase, tcw1, tcw2, rowp1, rowp2, cw1, cw2, nb, n);

    // ---- h0 for both branches ----
    hipLaunchKernelGGL(gemm_in_kernel, dim3((n + BM - 1) / BM, 2), dim3(256), 0, stream,
                       x, Win, bin, h1A, h2A, n);

    // ---- z2 init with fw0 * h0 projections ----
    hipLaunchKernelGGL(zacc2_kernel, dim3(rowBlocks), dim3(256), 0, stream,
                       h1A, h2A, Wout, fW, z2, n);

    // ---- K-hop propagation, both branches per dispatch (parity split) ----
    uint* cur1 = h1A; uint* nxt1 = h1B;
    uint* cur2 = h2A; uint* nxt2 = h2B;
    for (int k = 0; k < KHOPS; ++k) {
        const int storeH = (k < KHOPS - 1) ? 1 : 0;
        BrArgs A { rowp1, cw1, cur1, nxt1, Wout };
        BrArgs B { rowp2, cw2, cur2, nxt2, Wout + (size_t)HID * COUT };
        hipLaunchKernelGGL(spmm2_kernel, dim3(rowBlocks * 2), dim3(256), 0, stream,
                           A, B, fW, k, z2, storeH, n);
        uint* t1 = cur1; cur1 = nxt1; nxt1 = t1;
        uint* t2 = cur2; cur2 = nxt2; nxt2 = t2;
    }

    hipLaunchKernelGGL(logsm_kernel, dim3((n + 255) / 256), dim3(256), 0, stream,
                       z2, bout, zout, n);
}

// Round 5
// 2661.547 us; speedup vs baseline: 2.8873x; 1.1117x over previous
//
#include <hip/hip_runtime.h>

#define F_IN 512
#define HID 128
#define KHOPS 10
#define COUT 10
#define COLMASK 0x1FFFF   // n <= 131072

typedef unsigned int uint;
typedef unsigned short ushort;
typedef float f32x4 __attribute__((ext_vector_type(4)));
typedef short bf16x8 __attribute__((ext_vector_type(8)));

__device__ __forceinline__ uint f2bf1(float f) {
    uint u = __float_as_uint(f);
    return (u + 0x7fffu + ((u >> 16) & 1u)) >> 16;   // RNE
}
__device__ __forceinline__ uint packbf(float a, float b) {
    return f2bf1(a) | (f2bf1(b) << 16);
}
__device__ __forceinline__ float bflo(uint u) { return __uint_as_float(u << 16); }
__device__ __forceinline__ float bfhi(uint u) { return __uint_as_float(u & 0xffff0000u); }

// ---------------- W_in -> bf16, pre-swizzled into MFMA B-fragment lane order ----------------
// frag (br, s, c): lane l holds B[k = s*32 + (l>>4)*8 + j][col = c*16 + (l&15)], j=0..7
// stored at uint4 index ((br*16 + s)*8 + c)*64 + l
__global__ __launch_bounds__(256) void wprep_kernel(
    const float* __restrict__ Win, ushort* __restrict__ Wsw)
{
    const int t = blockIdx.x * blockDim.x + threadIdx.x;
    if (t >= 2 * 16 * 8 * 64) return;
    const int l = t & 63;
    const int c = (t >> 6) & 7;
    const int s = (t >> 9) & 15;
    const int br = t >> 13;
    const int col = c * 16 + (l & 15);
    const int k0 = s * 32 + (l >> 4) * 8;
    const float* W = Win + (size_t)br * F_IN * HID;
    uint o0 = packbf(W[(size_t)(k0 + 0) * HID + col], W[(size_t)(k0 + 1) * HID + col]);
    uint o1 = packbf(W[(size_t)(k0 + 2) * HID + col], W[(size_t)(k0 + 3) * HID + col]);
    uint o2 = packbf(W[(size_t)(k0 + 4) * HID + col], W[(size_t)(k0 + 5) * HID + col]);
    uint o3 = packbf(W[(size_t)(k0 + 6) * HID + col], W[(size_t)(k0 + 7) * HID + col]);
    *(uint4*)(Wsw + (size_t)t * 8) = make_uint4(o0, o1, o2, o3);
}

// ---------------- GEMM via MFMA: h = bf16(x @ W + b), both branches via blockIdx.y ----------------
// 256 threads = 4 waves; wave handles 32 rows (2 frags of 16); block tile 128 rows x 128 cols.
__global__ __launch_bounds__(256) void gemm_mfma_kernel(
    const float* __restrict__ x, const ushort* __restrict__ Wsw,
    const float* __restrict__ bin, uint* __restrict__ h1, uint* __restrict__ h2, int n)
{
    const int br = blockIdx.y;
    const uint4* Wb = (const uint4*)(Wsw + (size_t)br * 16 * 8 * 64 * 8);
    const float* bias = bin + br * HID;
    uint* h = br ? h2 : h1;

    const int w = threadIdx.x >> 6;
    const int lane = threadIdx.x & 63;
    const int r16 = lane & 15;
    const int kg = lane >> 4;            // 0..3

    const int rowbase = blockIdx.x * 128 + w * 32;

    f32x4 acc[2][8];
#pragma unroll
    for (int f = 0; f < 2; ++f)
#pragma unroll
        for (int c = 0; c < 8; ++c) acc[f][c] = (f32x4)0.f;

    int rA0 = rowbase + r16;      if (rA0 > n - 1) rA0 = n - 1;
    int rA1 = rowbase + 16 + r16; if (rA1 > n - 1) rA1 = n - 1;
    const float* xp0 = x + (size_t)rA0 * F_IN + kg * 8;
    const float* xp1 = x + (size_t)rA1 * F_IN + kg * 8;

    for (int s = 0; s < 16; ++s) {
        const float4 a0lo = *(const float4*)(xp0 + s * 32);
        const float4 a0hi = *(const float4*)(xp0 + s * 32 + 4);
        const float4 a1lo = *(const float4*)(xp1 + s * 32);
        const float4 a1hi = *(const float4*)(xp1 + s * 32 + 4);
        union { uint4 u; bf16x8 v; } af0, af1;
        af0.u = make_uint4(packbf(a0lo.x, a0lo.y), packbf(a0lo.z, a0lo.w),
                           packbf(a0hi.x, a0hi.y), packbf(a0hi.z, a0hi.w));
        af1.u = make_uint4(packbf(a1lo.x, a1lo.y), packbf(a1lo.z, a1lo.w),
                           packbf(a1hi.x, a1hi.y), packbf(a1hi.z, a1hi.w));
        const uint4* wq = Wb + (size_t)(s * 8) * 64 + lane;
#pragma unroll
        for (int c = 0; c < 8; ++c) {
            union { uint4 u; bf16x8 v; } bfr;
            bfr.u = wq[c * 64];
            acc[0][c] = __builtin_amdgcn_mfma_f32_16x16x32_bf16(af0.v, bfr.v, acc[0][c], 0, 0, 0);
            acc[1][c] = __builtin_amdgcn_mfma_f32_16x16x32_bf16(af1.v, bfr.v, acc[1][c], 0, 0, 0);
        }
    }

    float bv[8];
#pragma unroll
    for (int c = 0; c < 8; ++c) bv[c] = bias[c * 16 + r16];

#pragma unroll
    for (int f = 0; f < 2; ++f)
#pragma unroll
        for (int c = 0; c < 8; ++c)
#pragma unroll
            for (int i = 0; i < 4; ++i) {
                const float v = acc[f][c][i] + bv[c];
                const float o = __shfl_xor(v, 1);
                const int row = rowbase + f * 16 + kg * 4 + i;
                if (!(lane & 1) && row < n)
                    h[(size_t)row * 64 + c * 8 + (r16 >> 1)] = packbf(v, o);
            }
}

// ---------------- CSR build ----------------
__global__ void bhist_kernel(const int* __restrict__ r1, int E1,
                             const int* __restrict__ r2, int E2,
                             int* __restrict__ bcnt, int nb)
{
    extern __shared__ int sh[];
    const int br = blockIdx.y;
    const int* rows = br ? r2 : r1;
    const int E = br ? E2 : E1;
    int* bc = bcnt + (size_t)br * nb;
    for (int i = threadIdx.x; i < nb; i += blockDim.x) sh[i] = 0;
    __syncthreads();
    for (int i = blockIdx.x * blockDim.x + threadIdx.x; i < E; i += gridDim.x * blockDim.x)
        atomicAdd(&sh[rows[i] >> 6], 1);
    __syncthreads();
    for (int i = threadIdx.x; i < nb; i += blockDim.x)
        if (sh[i]) atomicAdd(&bc[i], sh[i]);
}

__global__ __launch_bounds__(256) void bscan_kernel(
    const int* __restrict__ bcnt, int* __restrict__ bbase, int* __restrict__ bcur,
    int* __restrict__ rowp1, int* __restrict__ rowp2,
    int nb, int n, int E1, int E2)
{
    __shared__ int ssum[256];
    const int br = blockIdx.y;
    const int* bc = bcnt + (size_t)br * nb;
    int* bb = bbase + (size_t)br * (nb + 1);
    int* cur = bcur + (size_t)br * nb;
    int* rowp = br ? rowp2 : rowp1;
    const int E = br ? E2 : E1;
    const int t = threadIdx.x;
    const int chunk = (nb + 255) / 256;
    const int start = t * chunk;
    const int end = (start + chunk < nb) ? start + chunk : nb;
    int sum = 0;
    for (int i = start; i < end; ++i) sum += bc[i];
    ssum[t] = sum;
    __syncthreads();
    if (t == 0) {
        int run = 0;
        for (int i = 0; i < 256; ++i) { int v = ssum[i]; ssum[i] = run; run += v; }
        bb[nb] = E;
        rowp[n] = E;
    }
    __syncthreads();
    int run = ssum[t];
    for (int i = start; i < end; ++i) {
        bb[i] = run; cur[i] = run; run += bc[i];
    }
}

#define SCAT_BLOCKS 256
__global__ __launch_bounds__(256) void bscat_kernel(
    const int* __restrict__ r1, const int* __restrict__ c1, const float* __restrict__ w1, int E1,
    const int* __restrict__ r2, const int* __restrict__ c2, const float* __restrict__ w2, int E2,
    int* __restrict__ bcur, int2* __restrict__ t1, int2* __restrict__ t2, int nb)
{
    extern __shared__ int sh[];
    int* lh = sh;
    int* lbase = sh + nb;
    const int br = blockIdx.y;
    const int* rows = br ? r2 : r1;
    const int* cols = br ? c2 : c1;
    const float* w  = br ? w2 : w1;
    const int E = br ? E2 : E1;
    int* cur = bcur + (size_t)br * nb;
    int2* tcw = br ? t2 : t1;
    const int t = threadIdx.x;

    for (int i = t; i < nb; i += 256) lh[i] = 0;
    __syncthreads();

    const int per = (E + SCAT_BLOCKS - 1) / SCAT_BLOCKS;
    const int c0 = blockIdx.x * per;
    const int cend = (c0 + per < E) ? c0 + per : E;

    for (int i = c0 + t; i < cend; i += 256)
        atomicAdd(&lh[rows[i] >> 6], 1);
    __syncthreads();
    for (int b = t; b < nb; b += 256) {
        int c = lh[b];
        lbase[b] = c ? atomicAdd(&cur[b], c) : 0;
        lh[b] = 0;
    }
    __syncthreads();
    for (int i = c0 + t; i < cend; i += 256) {
        int r = rows[i];
        int b = r >> 6;
        int p = atomicAdd(&lh[b], 1);
        uint lo = (uint)cols[i] | ((uint)(r & 63) << 17);
        tcw[lbase[b] + p] = make_int2((int)lo, __float_as_int(w[i]));
    }
}

__global__ __launch_bounds__(256) void bsort_kernel(
    const int* __restrict__ bbase,
    const int2* __restrict__ t1, const int2* __restrict__ t2,
    int* __restrict__ rowp1, int* __restrict__ rowp2,
    int2* __restrict__ cw1, int2* __restrict__ cw2, int nb, int n)
{
    __shared__ int cnt[64], soff[64], pos[64];
    const int br = blockIdx.y;
    const int* bb = bbase + (size_t)br * (nb + 1);
    const int2* tcw = br ? t2 : t1;
    int* rowp = br ? rowp2 : rowp1;
    int2* cw = br ? cw2 : cw1;
    const int b = blockIdx.x;
    const int t = threadIdx.x;
    const int base = bb[b];
    const int m = bb[b + 1] - base;
    if (t < 64) cnt[t] = 0;
    __syncthreads();
    for (int i = t; i < m; i += 256) atomicAdd(&cnt[((uint)tcw[base + i].x >> 17) & 63], 1);
    __syncthreads();
    if (t == 0) {
        int run = 0;
#pragma unroll
        for (int r = 0; r < 64; ++r) { soff[r] = run; run += cnt[r]; }
    }
    __syncthreads();
    if (t < 64) {
        pos[t] = soff[t];
        int g = b * 64 + t;
        if (g < n) rowp[g] = base + soff[t];
    }
    __syncthreads();
    for (int i = t; i < m; i += 256) {
        int2 e = tcw[base + i];
        int r = ((uint)e.x >> 17) & 63;
        int p = atomicAdd(&pos[r], 1);
        cw[base + p] = e;
    }
}

// ---------------- SpMM (bf16 gather, readlane edge broadcast) + fused z2 ----------------
struct BrArgs {
    const int* rowp;
    const int2* cw;
    const uint* hin;
    uint* hout;
    const float* Wo;
};

__global__ __launch_bounds__(256) void spmm2_kernel(
    BrArgs A, BrArgs B, const float* __restrict__ fW, int k,
    float* __restrict__ z2, int storeH, int n)
{
    const int bid = blockIdx.x;
    const int br = bid & 1;
    const int wid = (bid >> 1) * 4 + (threadIdx.x >> 6);
    if (wid >= n) return;
    const int*   rowp = br ? B.rowp : A.rowp;
    const int2*  cw   = br ? B.cw   : A.cw;
    const uint*  hin  = br ? B.hin  : A.hin;
    uint*        hout = br ? B.hout : A.hout;
    const float* Wo   = br ? B.Wo   : A.Wo;
    const int lane = threadIdx.x & 63;

    float w0[COUT], w1[COUT];
    const float* wp = Wo + (size_t)(lane * 2) * COUT;
#pragma unroll
    for (int c = 0; c < COUT; ++c) { w0[c] = wp[c]; w1[c] = wp[COUT + c]; }

    const int s = rowp[wid];
    const int e = rowp[wid + 1];
    const uint* hb = hin + lane;

    float2 acc = make_float2(0.f, 0.f);
    int i = s;
    while (i < e) {
        const int rem = e - i;
        const int cnt = rem < 64 ? rem : 64;
        int2 my = make_int2(0, 0);
        if (lane < cnt) my = cw[i + lane];
        int j = 0;
        for (; j + 3 < cnt; j += 4) {
            const int x0 = __builtin_amdgcn_readlane(my.x, j);
            const int y0 = __builtin_amdgcn_readlane(my.y, j);
            const int x1 = __builtin_amdgcn_readlane(my.x, j + 1);
            const int y1 = __builtin_amdgcn_readlane(my.y, j + 1);
            const int x2 = __builtin_amdgcn_readlane(my.x, j + 2);
            const int y2 = __builtin_amdgcn_readlane(my.y, j + 2);
            const int x3 = __builtin_amdgcn_readlane(my.x, j + 3);
            const int y3 = __builtin_amdgcn_readlane(my.y, j + 3);
            const uint g0 = hb[(size_t)(x0 & COLMASK) * 64];
            const uint g1 = hb[(size_t)(x1 & COLMASK) * 64];
            const uint g2 = hb[(size_t)(x2 & COLMASK) * 64];
            const uint g3 = hb[(size_t)(x3 & COLMASK) * 64];
            const float q0 = __int_as_float(y0), q1 = __int_as_float(y1);
            const float q2 = __int_as_float(y2), q3 = __int_as_float(y3);
            acc.x = fmaf(q0, bflo(g0), acc.x); acc.y = fmaf(q0, bfhi(g0), acc.y);
            acc.x = fmaf(q1, bflo(g1), acc.x); acc.y = fmaf(q1, bfhi(g1), acc.y);
            acc.x = fmaf(q2, bflo(g2), acc.x); acc.y = fmaf(q2, bfhi(g2), acc.y);
            acc.x = fmaf(q3, bflo(g3), acc.x); acc.y = fmaf(q3, bfhi(g3), acc.y);
        }
        for (; j < cnt; ++j) {
            const int xj = __builtin_amdgcn_readlane(my.x, j);
            const int yj = __builtin_amdgcn_readlane(my.y, j);
            const uint g = hb[(size_t)(xj & COLMASK) * 64];
            const float q = __int_as_float(yj);
            acc.x = fmaf(q, bflo(g), acc.x);
            acc.y = fmaf(q, bfhi(g), acc.y);
        }
        i += cnt;
    }

    if (storeH)
        hout[(size_t)wid * 64 + lane] = packbf(acc.x, acc.y);

    const float fw = fW[br * (KHOPS + 1) + k + 1];
    float zadd = 0.f;
#pragma unroll
    for (int c = 0; c < COUT; ++c) {
        float pp = fmaf(acc.x, w0[c], acc.y * w1[c]);
#pragma unroll
        for (int off = 32; off; off >>= 1) pp += __shfl_xor(pp, off);
        if (lane == c) zadd = pp;
    }
    if (lane < COUT) {
        const size_t o = (size_t)wid * (2 * COUT) + br * COUT + lane;
        z2[o] += fw * zadd;
    }
}

// ---------------- z2 init: fw0 * (h0 @ Wout) per branch ----------------
__global__ __launch_bounds__(256) void zacc2_kernel(
    const uint* __restrict__ h1, const uint* __restrict__ h2,
    const float* __restrict__ Wout, const float* __restrict__ fW,
    float* __restrict__ z2, int n)
{
    const int wid = (blockIdx.x * blockDim.x + threadIdx.x) >> 6;
    if (wid >= n) return;
    const int lane = threadIdx.x & 63;
    const uint u1 = h1[(size_t)wid * 64 + lane];
    const uint u2 = h2[(size_t)wid * 64 + lane];
    const float a1 = bflo(u1), b1v = bfhi(u1);
    const float a2 = bflo(u2), b2v = bfhi(u2);
    const float* wp1 = Wout + (size_t)(lane * 2) * COUT;
    const float* wp2 = Wout + (size_t)HID * COUT + (size_t)(lane * 2) * COUT;
    float zv1 = 0.f, zv2 = 0.f;
#pragma unroll
    for (int c = 0; c < COUT; ++c) {
        float p1 = fmaf(a1, wp1[c], b1v * wp1[COUT + c]);
        float p2 = fmaf(a2, wp2[c], b2v * wp2[COUT + c]);
#pragma unroll
        for (int off = 32; off; off >>= 1) { p1 += __shfl_xor(p1, off); p2 += __shfl_xor(p2, off); }
        if (lane == c) { zv1 = p1; zv2 = p2; }
    }
    if (lane < COUT) {
        z2[(size_t)wid * (2 * COUT) + lane]        = fW[0] * zv1;
        z2[(size_t)wid * (2 * COUT) + COUT + lane] = fW[KHOPS + 1] * zv2;
    }
}

// ---------------- log_softmax(z2_br0 + z2_br1 + bias) ----------------
__global__ void logsm_kernel(const float* __restrict__ z2, const float* __restrict__ bout,
                             float* __restrict__ out, int n)
{
    const int r = blockIdx.x * blockDim.x + threadIdx.x;
    if (r >= n) return;
    float v[COUT];
    float m = -1e30f;
#pragma unroll
    for (int c = 0; c < COUT; ++c) {
        v[c] = z2[(size_t)r * (2 * COUT) + c] + z2[(size_t)r * (2 * COUT) + COUT + c] + bout[c];
        m = fmaxf(m, v[c]);
    }
    float s = 0.f;
#pragma unroll
    for (int c = 0; c < COUT; ++c) s += expf(v[c] - m);
    const float l = logf(s) + m;
#pragma unroll
    for (int c = 0; c < COUT; ++c) out[(size_t)r * COUT + c] = v[c] - l;
}

extern "C" void kernel_launch(void* const* d_in, const int* in_sizes, int n_in,
                              void* d_out, int out_size, void* d_ws, size_t ws_size,
                              hipStream_t stream)
{
    const float* x    = (const float*)d_in[0];
    const int*   ei1  = (const int*)d_in[1];
    const float* ew1  = (const float*)d_in[2];
    const int*   ei2  = (const int*)d_in[3];
    const float* ew2  = (const float*)d_in[4];
    const float* Win  = (const float*)d_in[5];
    const float* bin  = (const float*)d_in[6];
    const float* fW   = (const float*)d_in[7];
    const float* Wout = (const float*)d_in[8];
    const float* bout = (const float*)d_in[9];
    const int n  = in_sizes[0] / F_IN;
    const int E1 = in_sizes[2];
    const int E2 = in_sizes[4];
    const int Emax = E1 > E2 ? E1 : E2;
    const int nb = (n + 63) / 64;
    float* zout = (float*)d_out;

    char* p = (char*)d_ws;
    auto alloc = [&](size_t bytes) { char* r = p; p += (bytes + 255) & ~(size_t)255; return r; };
    char* regA = alloc((size_t)4 * n * 64 * 4);
    uint* h1A = (uint*)regA;
    uint* h1B = (uint*)(regA + (size_t)n * 64 * 4);
    uint* h2A = (uint*)(regA + (size_t)2 * n * 64 * 4);
    uint* h2B = (uint*)(regA + (size_t)3 * n * 64 * 4);
    int2* tcw1 = (int2*)regA;
    int2* tcw2 = (int2*)(regA + (size_t)Emax * 8);
    int2* cw1  = (int2*)alloc((size_t)Emax * 8);
    int2* cw2  = (int2*)alloc((size_t)Emax * 8);
    int*  rowp1 = (int*)alloc((size_t)(n + 1) * 4);
    int*  rowp2 = (int*)alloc((size_t)(n + 1) * 4);
    float* z2  = (float*)alloc((size_t)n * 2 * COUT * 4);
    int*  bcnt  = (int*)alloc((size_t)2 * nb * 4);
    int*  bbase = (int*)alloc((size_t)2 * (nb + 1) * 4);
    int*  bcur  = (int*)alloc((size_t)2 * nb * 4);
    ushort* Wsw = (ushort*)alloc((size_t)2 * 16 * 8 * 64 * 8 * 2);   // 256 KB

    const int rowBlocks = (n + 3) / 4;

    // ---- W prep (independent of CSR build) ----
    hipLaunchKernelGGL(wprep_kernel, dim3(64), dim3(256), 0, stream, Win, Wsw);

    // ---- CSR build, both branches per dispatch ----
    hipMemsetAsync(bcnt, 0, (size_t)2 * nb * 4, stream);
    hipLaunchKernelGGL(bhist_kernel, dim3(256, 2), dim3(256), nb * 4, stream,
                       ei1, E1, ei2, E2, bcnt, nb);
    hipLaunchKernelGGL(bscan_kernel, dim3(1, 2), dim3(256), 0, stream,
                       bcnt, bbase, bcur, rowp1, rowp2, nb, n, E1, E2);
    hipLaunchKernelGGL(bscat_kernel, dim3(SCAT_BLOCKS, 2), dim3(256), 2 * nb * 4, stream,
                       ei1, ei1 + E1, ew1, E1, ei2, ei2 + E2, ew2, E2,
                       bcur, tcw1, tcw2, nb);
    hipLaunchKernelGGL(bsort_kernel, dim3(nb, 2), dim3(256), 0, stream,
                       bbase, tcw1, tcw2, rowp1, rowp2, cw1, cw2, nb, n);

    // ---- h0 for both branches (MFMA) ----
    hipLaunchKernelGGL(gemm_mfma_kernel, dim3((n + 127) / 128, 2), dim3(256), 0, stream,
                       x, Wsw, bin, h1A, h2A, n);

    // ---- z2 init with fw0 * h0 projections ----
    hipLaunchKernelGGL(zacc2_kernel, dim3(rowBlocks), dim3(256), 0, stream,
                       h1A, h2A, Wout, fW, z2, n);

    // ---- K-hop propagation, both branches per dispatch (parity split) ----
    uint* cur1 = h1A; uint* nxt1 = h1B;
    uint* cur2 = h2A; uint* nxt2 = h2B;
    for (int k = 0; k < KHOPS; ++k) {
        const int storeH = (k < KHOPS - 1) ? 1 : 0;
        BrArgs A { rowp1, cw1, cur1, nxt1, Wout };
        BrArgs B { rowp2, cw2, cur2, nxt2, Wout + (size_t)HID * COUT };
        hipLaunchKernelGGL(spmm2_kernel, dim3(rowBlocks * 2), dim3(256), 0, stream,
                           A, B, fW, k, z2, storeH, n);
        uint* t1 = cur1; cur1 = nxt1; nxt1 = t1;
        uint* t2 = cur2; cur2 = nxt2; nxt2 = t2;
    }

    hipLaunchKernelGGL(logsm_kernel, dim3((n + 255) / 256, 1), dim3(256), 0, stream,
                       z2, bout, zout, n);
}

// Round 6
// 2640.660 us; speedup vs baseline: 2.9102x; 1.0079x over previous
//
#include <hip/hip_runtime.h>

#define F_IN 512
#define HID 128
#define KHOPS 10
#define COUT 10

typedef unsigned int uint;
typedef unsigned short ushort;
typedef float f32x4 __attribute__((ext_vector_type(4)));
typedef short bf16x8 __attribute__((ext_vector_type(8)));

__device__ __forceinline__ uint f2bf1(float f) {
    uint u = __float_as_uint(f);
    return (u + 0x7fffu + ((u >> 16) & 1u)) >> 16;   // RNE
}
__device__ __forceinline__ uint packbf(float a, float b) {
    return f2bf1(a) | (f2bf1(b) << 16);
}
__device__ __forceinline__ float bflo(uint u) { return __uint_as_float(u << 16); }
__device__ __forceinline__ float bfhi(uint u) { return __uint_as_float(u & 0xffff0000u); }

// ---------------- W_in -> bf16, pre-swizzled into MFMA B-fragment lane order ----------------
__global__ __launch_bounds__(256) void wprep_kernel(
    const float* __restrict__ Win, ushort* __restrict__ Wsw)
{
    const int t = blockIdx.x * blockDim.x + threadIdx.x;
    if (t >= 2 * 16 * 8 * 64) return;
    const int l = t & 63;
    const int c = (t >> 6) & 7;
    const int s = (t >> 9) & 15;
    const int br = t >> 13;
    const int col = c * 16 + (l & 15);
    const int k0 = s * 32 + (l >> 4) * 8;
    const float* W = Win + (size_t)br * F_IN * HID;
    uint o0 = packbf(W[(size_t)(k0 + 0) * HID + col], W[(size_t)(k0 + 1) * HID + col]);
    uint o1 = packbf(W[(size_t)(k0 + 2) * HID + col], W[(size_t)(k0 + 3) * HID + col]);
    uint o2 = packbf(W[(size_t)(k0 + 4) * HID + col], W[(size_t)(k0 + 5) * HID + col]);
    uint o3 = packbf(W[(size_t)(k0 + 6) * HID + col], W[(size_t)(k0 + 7) * HID + col]);
    *(uint4*)(Wsw + (size_t)t * 8) = make_uint4(o0, o1, o2, o3);
}

// ---------------- GEMM via MFMA: h = bf16(x @ W + b) ----------------
__global__ __launch_bounds__(256) void gemm_mfma_kernel(
    const float* __restrict__ x, const ushort* __restrict__ Wsw,
    const float* __restrict__ bin, uint* __restrict__ h1, uint* __restrict__ h2, int n)
{
    const int br = blockIdx.y;
    const uint4* Wb = (const uint4*)(Wsw + (size_t)br * 16 * 8 * 64 * 8);
    const float* bias = bin + br * HID;
    uint* h = br ? h2 : h1;

    const int w = threadIdx.x >> 6;
    const int lane = threadIdx.x & 63;
    const int r16 = lane & 15;
    const int kg = lane >> 4;

    const int rowbase = blockIdx.x * 128 + w * 32;

    f32x4 acc[2][8];
#pragma unroll
    for (int f = 0; f < 2; ++f)
#pragma unroll
        for (int c = 0; c < 8; ++c) acc[f][c] = (f32x4)0.f;

    int rA0 = rowbase + r16;      if (rA0 > n - 1) rA0 = n - 1;
    int rA1 = rowbase + 16 + r16; if (rA1 > n - 1) rA1 = n - 1;
    const float* xp0 = x + (size_t)rA0 * F_IN + kg * 8;
    const float* xp1 = x + (size_t)rA1 * F_IN + kg * 8;

    for (int s = 0; s < 16; ++s) {
        const float4 a0lo = *(const float4*)(xp0 + s * 32);
        const float4 a0hi = *(const float4*)(xp0 + s * 32 + 4);
        const float4 a1lo = *(const float4*)(xp1 + s * 32);
        const float4 a1hi = *(const float4*)(xp1 + s * 32 + 4);
        union { uint4 u; bf16x8 v; } af0, af1;
        af0.u = make_uint4(packbf(a0lo.x, a0lo.y), packbf(a0lo.z, a0lo.w),
                           packbf(a0hi.x, a0hi.y), packbf(a0hi.z, a0hi.w));
        af1.u = make_uint4(packbf(a1lo.x, a1lo.y), packbf(a1lo.z, a1lo.w),
                           packbf(a1hi.x, a1hi.y), packbf(a1hi.z, a1hi.w));
        const uint4* wq = Wb + (size_t)(s * 8) * 64 + lane;
#pragma unroll
        for (int c = 0; c < 8; ++c) {
            union { uint4 u; bf16x8 v; } bfr;
            bfr.u = wq[c * 64];
            acc[0][c] = __builtin_amdgcn_mfma_f32_16x16x32_bf16(af0.v, bfr.v, acc[0][c], 0, 0, 0);
            acc[1][c] = __builtin_amdgcn_mfma_f32_16x16x32_bf16(af1.v, bfr.v, acc[1][c], 0, 0, 0);
        }
    }

    float bv[8];
#pragma unroll
    for (int c = 0; c < 8; ++c) bv[c] = bias[c * 16 + r16];

#pragma unroll
    for (int f = 0; f < 2; ++f)
#pragma unroll
        for (int c = 0; c < 8; ++c)
#pragma unroll
            for (int i = 0; i < 4; ++i) {
                const float v = acc[f][c][i] + bv[c];
                const float o = __shfl_xor(v, 1);
                const int row = rowbase + f * 16 + kg * 4 + i;
                if (!(lane & 1) && row < n)
                    h[(size_t)row * 64 + c * 8 + (r16 >> 1)] = packbf(v, o);
            }
}

// ---------------- CSR build ----------------
// Packed edge record (temp): lo = (col << 8) | rowlocal, hi = w bits.
// Final cw record: lo = col*256 (byte offset into a 256B h row), hi = w bits.

__global__ void bhist_kernel(const int* __restrict__ r1, int E1,
                             const int* __restrict__ r2, int E2,
                             int* __restrict__ bcnt, int nb)
{
    extern __shared__ int sh[];
    const int br = blockIdx.y;
    const int* rows = br ? r2 : r1;
    const int E = br ? E2 : E1;
    int* bc = bcnt + (size_t)br * nb;
    for (int i = threadIdx.x; i < nb; i += blockDim.x) sh[i] = 0;
    __syncthreads();
    for (int i = blockIdx.x * blockDim.x + threadIdx.x; i < E; i += gridDim.x * blockDim.x)
        atomicAdd(&sh[rows[i] >> 6], 1);
    __syncthreads();
    for (int i = threadIdx.x; i < nb; i += blockDim.x)
        if (sh[i]) atomicAdd(&bc[i], sh[i]);
}

__global__ __launch_bounds__(256) void bscan_kernel(
    const int* __restrict__ bcnt, int* __restrict__ bbase, int* __restrict__ bcur,
    int* __restrict__ rowp1, int* __restrict__ rowp2,
    int nb, int n, int E1, int E2)
{
    __shared__ int ssum[256];
    const int br = blockIdx.y;
    const int* bc = bcnt + (size_t)br * nb;
    int* bb = bbase + (size_t)br * (nb + 1);
    int* cur = bcur + (size_t)br * nb;
    int* rowp = br ? rowp2 : rowp1;
    const int E = br ? E2 : E1;
    const int t = threadIdx.x;
    const int chunk = (nb + 255) / 256;
    const int start = t * chunk;
    const int end = (start + chunk < nb) ? start + chunk : nb;
    int sum = 0;
    for (int i = start; i < end; ++i) sum += bc[i];
    ssum[t] = sum;
    __syncthreads();
    if (t == 0) {
        int run = 0;
        for (int i = 0; i < 256; ++i) { int v = ssum[i]; ssum[i] = run; run += v; }
        bb[nb] = E;
        rowp[n] = E;
    }
    __syncthreads();
    int run = ssum[t];
    for (int i = start; i < end; ++i) {
        bb[i] = run; cur[i] = run; run += bc[i];
    }
}

#define SCAT_BLOCKS 256
__global__ __launch_bounds__(256) void bscat_kernel(
    const int* __restrict__ r1, const int* __restrict__ c1, const float* __restrict__ w1, int E1,
    const int* __restrict__ r2, const int* __restrict__ c2, const float* __restrict__ w2, int E2,
    int* __restrict__ bcur, int2* __restrict__ t1, int2* __restrict__ t2, int nb)
{
    extern __shared__ int sh[];
    int* lh = sh;
    int* lbase = sh + nb;
    const int br = blockIdx.y;
    const int* rows = br ? r2 : r1;
    const int* cols = br ? c2 : c1;
    const float* w  = br ? w2 : w1;
    const int E = br ? E2 : E1;
    int* cur = bcur + (size_t)br * nb;
    int2* tcw = br ? t2 : t1;
    const int t = threadIdx.x;

    for (int i = t; i < nb; i += 256) lh[i] = 0;
    __syncthreads();

    const int per = (E + SCAT_BLOCKS - 1) / SCAT_BLOCKS;
    const int c0 = blockIdx.x * per;
    const int cend = (c0 + per < E) ? c0 + per : E;

    for (int i = c0 + t; i < cend; i += 256)
        atomicAdd(&lh[rows[i] >> 6], 1);
    __syncthreads();
    for (int b = t; b < nb; b += 256) {
        int c = lh[b];
        lbase[b] = c ? atomicAdd(&cur[b], c) : 0;
        lh[b] = 0;
    }
    __syncthreads();
    for (int i = c0 + t; i < cend; i += 256) {
        int r = rows[i];
        int b = r >> 6;
        int p = atomicAdd(&lh[b], 1);
        uint lo = ((uint)cols[i] << 8) | (uint)(r & 63);
        tcw[lbase[b] + p] = make_int2((int)lo, __float_as_int(w[i]));
    }
}

__global__ __launch_bounds__(256) void bsort_kernel(
    const int* __restrict__ bbase,
    const int2* __restrict__ t1, const int2* __restrict__ t2,
    int* __restrict__ rowp1, int* __restrict__ rowp2,
    int2* __restrict__ cw1, int2* __restrict__ cw2, int nb, int n)
{
    __shared__ int cnt[64], soff[64], pos[64];
    const int br = blockIdx.y;
    const int* bb = bbase + (size_t)br * (nb + 1);
    const int2* tcw = br ? t2 : t1;
    int* rowp = br ? rowp2 : rowp1;
    int2* cw = br ? cw2 : cw1;
    const int b = blockIdx.x;
    const int t = threadIdx.x;
    const int base = bb[b];
    const int m = bb[b + 1] - base;
    if (t < 64) cnt[t] = 0;
    __syncthreads();
    for (int i = t; i < m; i += 256) atomicAdd(&cnt[(uint)tcw[base + i].x & 63], 1);
    __syncthreads();
    if (t == 0) {
        int run = 0;
#pragma unroll
        for (int r = 0; r < 64; ++r) { soff[r] = run; run += cnt[r]; }
    }
    __syncthreads();
    if (t < 64) {
        pos[t] = soff[t];
        int g = b * 64 + t;
        if (g < n) rowp[g] = base + soff[t];
    }
    __syncthreads();
    for (int i = t; i < m; i += 256) {
        int2 e = tcw[base + i];
        int r = (uint)e.x & 63;
        int p = atomicAdd(&pos[r], 1);
        cw[base + p] = make_int2((int)((uint)e.x & 0xFFFFFF00u), e.y);  // col*256 byte offset
    }
}

// ---------------- SpMM (bf16 gather, scalar-base addressing) + fused z2 ----------------
struct BrArgs {
    const int* rowp;
    const int2* cw;
    const uint* hin;
    uint* hout;
    const float* Wo;
};

__global__ __launch_bounds__(256) void spmm2_kernel(
    BrArgs A, BrArgs B, const float* __restrict__ fW, int k,
    float* __restrict__ z2, int storeH, int n)
{
    const int bid = blockIdx.x;
    const int br = bid & 1;
    const int wid = (bid >> 1) * 4 + (threadIdx.x >> 6);
    if (wid >= n) return;
    const int*   rowp = br ? B.rowp : A.rowp;
    const int2*  cw   = br ? B.cw   : A.cw;
    const uint*  hin  = br ? B.hin  : A.hin;
    uint*        hout = br ? B.hout : A.hout;
    const float* Wo   = br ? B.Wo   : A.Wo;
    const int lane = threadIdx.x & 63;
    const int laneB = lane * 4;                       // per-lane byte offset within a row
    const char* hbase = (const char*)hin;

    float w0[COUT], w1[COUT];
    const float* wp = Wo + (size_t)(lane * 2) * COUT;
#pragma unroll
    for (int c = 0; c < COUT; ++c) { w0[c] = wp[c]; w1[c] = wp[COUT + c]; }

    const int s = rowp[wid];
    const int e = rowp[wid + 1];

    float2 acc = make_float2(0.f, 0.f);
    int i = s;
    while (i < e) {
        const int rem = e - i;
        const int cnt = rem < 64 ? rem : 64;
        int2 my = make_int2(0, 0);
        if (lane < cnt) my = cw[i + lane];
        int j = 0;
        for (; j + 3 < cnt; j += 4) {
            // readlane results are wave-uniform -> scalar base + per-lane 32b offset (saddr form)
            const uint b0 = (uint)__builtin_amdgcn_readlane(my.x, j);
            const uint b1 = (uint)__builtin_amdgcn_readlane(my.x, j + 1);
            const uint b2 = (uint)__builtin_amdgcn_readlane(my.x, j + 2);
            const uint b3 = (uint)__builtin_amdgcn_readlane(my.x, j + 3);
            const float q0 = __int_as_float(__builtin_amdgcn_readlane(my.y, j));
            const float q1 = __int_as_float(__builtin_amdgcn_readlane(my.y, j + 1));
            const float q2 = __int_as_float(__builtin_amdgcn_readlane(my.y, j + 2));
            const float q3 = __int_as_float(__builtin_amdgcn_readlane(my.y, j + 3));
            const uint g0 = *(const uint*)(hbase + b0 + laneB);
            const uint g1 = *(const uint*)(hbase + b1 + laneB);
            const uint g2 = *(const uint*)(hbase + b2 + laneB);
            const uint g3 = *(const uint*)(hbase + b3 + laneB);
            acc.x = fmaf(q0, bflo(g0), acc.x); acc.y = fmaf(q0, bfhi(g0), acc.y);
            acc.x = fmaf(q1, bflo(g1), acc.x); acc.y = fmaf(q1, bfhi(g1), acc.y);
            acc.x = fmaf(q2, bflo(g2), acc.x); acc.y = fmaf(q2, bfhi(g2), acc.y);
            acc.x = fmaf(q3, bflo(g3), acc.x); acc.y = fmaf(q3, bfhi(g3), acc.y);
        }
        for (; j < cnt; ++j) {
            const uint bj = (uint)__builtin_amdgcn_readlane(my.x, j);
            const float q = __int_as_float(__builtin_amdgcn_readlane(my.y, j));
            const uint g = *(const uint*)(hbase + bj + laneB);
            acc.x = fmaf(q, bflo(g), acc.x);
            acc.y = fmaf(q, bfhi(g), acc.y);
        }
        i += cnt;
    }

    if (storeH)
        hout[(size_t)wid * 64 + lane] = packbf(acc.x, acc.y);

    const float fw = fW[br * (KHOPS + 1) + k + 1];
    float zadd = 0.f;
#pragma unroll
    for (int c = 0; c < COUT; ++c) {
        float pp = fmaf(acc.x, w0[c], acc.y * w1[c]);
#pragma unroll
        for (int off = 32; off; off >>= 1) pp += __shfl_xor(pp, off);
        if (lane == c) zadd = pp;
    }
    if (lane < COUT) {
        const size_t o = (size_t)wid * (2 * COUT) + br * COUT + lane;
        z2[o] += fw * zadd;
    }
}

// ---------------- z2 init: fw0 * (h0 @ Wout) per branch ----------------
__global__ __launch_bounds__(256) void zacc2_kernel(
    const uint* __restrict__ h1, const uint* __restrict__ h2,
    const float* __restrict__ Wout, const float* __restrict__ fW,
    float* __restrict__ z2, int n)
{
    const int wid = (blockIdx.x * blockDim.x + threadIdx.x) >> 6;
    if (wid >= n) return;
    const int lane = threadIdx.x & 63;
    const uint u1 = h1[(size_t)wid * 64 + lane];
    const uint u2 = h2[(size_t)wid * 64 + lane];
    const float a1 = bflo(u1), b1v = bfhi(u1);
    const float a2 = bflo(u2), b2v = bfhi(u2);
    const float* wp1 = Wout + (size_t)(lane * 2) * COUT;
    const float* wp2 = Wout + (size_t)HID * COUT + (size_t)(lane * 2) * COUT;
    float zv1 = 0.f, zv2 = 0.f;
#pragma unroll
    for (int c = 0; c < COUT; ++c) {
        float p1 = fmaf(a1, wp1[c], b1v * wp1[COUT + c]);
        float p2 = fmaf(a2, wp2[c], b2v * wp2[COUT + c]);
#pragma unroll
        for (int off = 32; off; off >>= 1) { p1 += __shfl_xor(p1, off); p2 += __shfl_xor(p2, off); }
        if (lane == c) { zv1 = p1; zv2 = p2; }
    }
    if (lane < COUT) {
        z2[(size_t)wid * (2 * COUT) + lane]        = fW[0] * zv1;
        z2[(size_t)wid * (2 * COUT) + COUT + lane] = fW[KHOPS + 1] * zv2;
    }
}

// ---------------- log_softmax(z2_br0 + z2_br1 + bias) ----------------
__global__ void logsm_kernel(const float* __restrict__ z2, const float* __restrict__ bout,
                             float* __restrict__ out, int n)
{
    const int r = blockIdx.x * blockDim.x + threadIdx.x;
    if (r >= n) return;
    float v[COUT];
    float m = -1e30f;
#pragma unroll
    for (int c = 0; c < COUT; ++c) {
        v[c] = z2[(size_t)r * (2 * COUT) + c] + z2[(size_t)r * (2 * COUT) + COUT + c] + bout[c];
        m = fmaxf(m, v[c]);
    }
    float s = 0.f;
#pragma unroll
    for (int c = 0; c < COUT; ++c) s += expf(v[c] - m);
    const float l = logf(s) + m;
#pragma unroll
    for (int c = 0; c < COUT; ++c) out[(size_t)r * COUT + c] = v[c] - l;
}

extern "C" void kernel_launch(void* const* d_in, const int* in_sizes, int n_in,
                              void* d_out, int out_size, void* d_ws, size_t ws_size,
                              hipStream_t stream)
{
    const float* x    = (const float*)d_in[0];
    const int*   ei1  = (const int*)d_in[1];
    const float* ew1  = (const float*)d_in[2];
    const int*   ei2  = (const int*)d_in[3];
    const float* ew2  = (const float*)d_in[4];
    const float* Win  = (const float*)d_in[5];
    const float* bin  = (const float*)d_in[6];
    const float* fW   = (const float*)d_in[7];
    const float* Wout = (const float*)d_in[8];
    const float* bout = (const float*)d_in[9];
    const int n  = in_sizes[0] / F_IN;
    const int E1 = in_sizes[2];
    const int E2 = in_sizes[4];
    const int Emax = E1 > E2 ? E1 : E2;
    const int nb = (n + 63) / 64;
    float* zout = (float*)d_out;

    char* p = (char*)d_ws;
    auto alloc = [&](size_t bytes) { char* r = p; p += (bytes + 255) & ~(size_t)255; return r; };
    char* regA = alloc((size_t)4 * n * 64 * 4);
    uint* h1A = (uint*)regA;
    uint* h1B = (uint*)(regA + (size_t)n * 64 * 4);
    uint* h2A = (uint*)(regA + (size_t)2 * n * 64 * 4);
    uint* h2B = (uint*)(regA + (size_t)3 * n * 64 * 4);
    int2* tcw1 = (int2*)regA;
    int2* tcw2 = (int2*)(regA + (size_t)Emax * 8);
    int2* cw1  = (int2*)alloc((size_t)Emax * 8);
    int2* cw2  = (int2*)alloc((size_t)Emax * 8);
    int*  rowp1 = (int*)alloc((size_t)(n + 1) * 4);
    int*  rowp2 = (int*)alloc((size_t)(n + 1) * 4);
    float* z2  = (float*)alloc((size_t)n * 2 * COUT * 4);
    int*  bcnt  = (int*)alloc((size_t)2 * nb * 4);
    int*  bbase = (int*)alloc((size_t)2 * (nb + 1) * 4);
    int*  bcur  = (int*)alloc((size_t)2 * nb * 4);
    ushort* Wsw = (ushort*)alloc((size_t)2 * 16 * 8 * 64 * 8 * 2);

    const int rowBlocks = (n + 3) / 4;

    hipLaunchKernelGGL(wprep_kernel, dim3(64), dim3(256), 0, stream, Win, Wsw);

    hipMemsetAsync(bcnt, 0, (size_t)2 * nb * 4, stream);
    hipLaunchKernelGGL(bhist_kernel, dim3(256, 2), dim3(256), nb * 4, stream,
                       ei1, E1, ei2, E2, bcnt, nb);
    hipLaunchKernelGGL(bscan_kernel, dim3(1, 2), dim3(256), 0, stream,
                       bcnt, bbase, bcur, rowp1, rowp2, nb, n, E1, E2);
    hipLaunchKernelGGL(bscat_kernel, dim3(SCAT_BLOCKS, 2), dim3(256), 2 * nb * 4, stream,
                       ei1, ei1 + E1, ew1, E1, ei2, ei2 + E2, ew2, E2,
                       bcur, tcw1, tcw2, nb);
    hipLaunchKernelGGL(bsort_kernel, dim3(nb, 2), dim3(256), 0, stream,
                       bbase, tcw1, tcw2, rowp1, rowp2, cw1, cw2, nb, n);

    hipLaunchKernelGGL(gemm_mfma_kernel, dim3((n + 127) / 128, 2), dim3(256), 0, stream,
                       x, Wsw, bin, h1A, h2A, n);

    hipLaunchKernelGGL(zacc2_kernel, dim3(rowBlocks), dim3(256), 0, stream,
                       h1A, h2A, Wout, fW, z2, n);

    uint* cur1 = h1A; uint* nxt1 = h1B;
    uint* cur2 = h2A; uint* nxt2 = h2B;
    for (int k = 0; k < KHOPS; ++k) {
        const int storeH = (k < KHOPS - 1) ? 1 : 0;
        BrArgs A { rowp1, cw1, cur1, nxt1, Wout };
        BrArgs B { rowp2, cw2, cur2, nxt2, Wout + (size_t)HID * COUT };
        hipLaunchKernelGGL(spmm2_kernel, dim3(rowBlocks * 2), dim3(256), 0, stream,
                           A, B, fW, k, z2, storeH, n);
        uint* t1 = cur1; cur1 = nxt1; nxt1 = t1;
        uint* t2 = cur2; cur2 = nxt2; nxt2 = t2;
    }

    hipLaunchKernelGGL(logsm_kernel, dim3((n + 255) / 256), dim3(256), 0, stream,
                       z2, bout, zout, n);
}